// Round 2
// baseline (764.510 us; speedup 1.0000x reference)
//
#include <hip/hip_runtime.h>
#include <hip/hip_bf16.h>

// Problem constants (match reference)
#define NPTS 200000
#define BB   4
#define C3D  64
#define C2D  128
#define HH   96
#define WW   312
#define MID  128
#define OUTC 128

// bf16 weight sub-offsets (ushort elements)
#define WB_W1   0
#define WB_W2   8192
#define WB_AW1  24576
#define WB_AW2  57344
#define WB_FW   57472
#define WB_TOTAL 90240                     // ushorts = 45120 floats

// Fixed-point scale for deterministic integer atomics
#define FXS 1048576.0f
#define FXI (1.0 / 1048576.0)

// ws layout (float offsets). All stats are u64 fixed-point (2 floats each).
#define WS_S64    45120                    // 4096 u64  -> 8192 floats
#define WS_CS64   53312                    // 64 u64    -> 128 floats
#define WS_SUM64  53440                    // 128*16 u64-> 4096 floats
#define WS_SSQ64  57536                    // 128*16 u64-> 4096 floats
#define ZERO_N    16512                    // floats to zero: 45120..61632
#define WS_DERIV  61632                    // s1,sh1,s2,sh2 : 512
#define WS_IMG    62144                    // bf16 image, 15,335,424 ushorts

typedef __attribute__((ext_vector_type(8))) short s16x8;
typedef __attribute__((ext_vector_type(4))) float f32x4;

__device__ __forceinline__ ushort f2bf(float f) {
    unsigned u = __float_as_uint(f);
    unsigned r = (u + 0x7FFFu + ((u >> 16) & 1u)) >> 16;   // RNE
    return (ushort)r;
}
__device__ __forceinline__ float bf2f(ushort u) {
    return __uint_as_float(((unsigned)u) << 16);
}
__device__ __forceinline__ void atomic_fx(unsigned long long* p, float v) {
    atomicAdd(p, (unsigned long long)(long long)llrintf(v * FXS));
}
__device__ __forceinline__ s16x8 pack_bf8(float4 a, float4 b) {
    s16x8 v;
    v[0] = (short)f2bf(a.x); v[1] = (short)f2bf(a.y);
    v[2] = (short)f2bf(a.z); v[3] = (short)f2bf(a.w);
    v[4] = (short)f2bf(b.x); v[5] = (short)f2bf(b.y);
    v[6] = (short)f2bf(b.z); v[7] = (short)f2bf(b.w);
    return v;
}
// Same-wave LDS write->read ordering: drain lgkm, block compiler motion.
#define WAVE_LDS_FENCE() do { \
    asm volatile("s_waitcnt lgkmcnt(0)" ::: "memory"); \
    __builtin_amdgcn_sched_barrier(0); \
} while (0)

// ---------------------------------------------------------------------------
// K1: transpose image (B,C,H,W) -> (B,H,W,C) bf16, and zero the stats region
// ---------------------------------------------------------------------------
__global__ __launch_bounds__(256) void k_transpose(const float* __restrict__ img,
                                                   ushort* __restrict__ img_bf,
                                                   float* __restrict__ stats) {
    __shared__ float tile[32][33];
    int flat = blockIdx.x * 256 + threadIdx.x;
    if (flat < ZERO_N) stats[flat] = 0.f;

    int bid = blockIdx.x;
    int ct = bid & 3;  bid >>= 2;          // 4 channel tiles
    int wt = bid % 10; bid /= 10;          // 10 width tiles
    int h  = bid % HH;
    int b  = bid / HH;
    int tx = threadIdx.x & 31, ty = threadIdx.x >> 5;   // 32 x 8
    int w0 = wt * 32, c0 = ct * 32;

    #pragma unroll
    for (int i = 0; i < 4; i++) {
        int c = c0 + ty + 8 * i;
        int w = w0 + tx;
        float v = 0.f;
        if (w < WW) v = img[((b * C2D + c) * HH + h) * WW + w];
        tile[ty + 8 * i][tx] = v;
    }
    __syncthreads();
    #pragma unroll
    for (int i = 0; i < 4; i++) {
        int w = w0 + ty + 8 * i;
        int c = c0 + tx;
        if (w < WW) img_bf[((b * HH + h) * WW + w) * C2D + c] = f2bf(tile[tx][ty + 8 * i]);
    }
}

// ---------------------------------------------------------------------------
// K1b: convert weights to bf16 (row-major unchanged)
// ---------------------------------------------------------------------------
__global__ __launch_bounds__(256) void k_prepw(const float* __restrict__ w1,
                                               const float* __restrict__ w2,
                                               const float* __restrict__ aw1,
                                               const float* __restrict__ aw2,
                                               const float* __restrict__ fw,
                                               ushort* __restrict__ wb) {
    int i = blockIdx.x * 256 + threadIdx.x;
    if (i >= WB_TOTAL) return;
    float v;
    if      (i < WB_W2)  v = w1[i - WB_W1];
    else if (i < WB_AW1) v = w2[i - WB_W2];
    else if (i < WB_AW2) v = aw1[i - WB_AW1];
    else if (i < WB_FW)  v = aw2[i - WB_AW2];
    else                 v = fw[i - WB_FW];
    wb[i] = f2bf(v);
}

// ---------------------------------------------------------------------------
// K2: X^T X (64x64) + colsum, fixed-point u64 atomics (deterministic)
// ---------------------------------------------------------------------------
#define XTX_ROWS_PER_BLK 256
#define XTX_BLOCKS ((NPTS + XTX_ROWS_PER_BLK - 1) / XTX_ROWS_PER_BLK)   // 782

__global__ __launch_bounds__(256) void k_xtx(const float* __restrict__ x,
                                             unsigned long long* __restrict__ S64,
                                             unsigned long long* __restrict__ cs64) {
    __shared__ float xs[64 * 68];
    int t = threadIdx.x;
    int ti = t >> 4, tj = t & 15;
    float acc[4][4];
    #pragma unroll
    for (int a = 0; a < 4; a++)
        #pragma unroll
        for (int b = 0; b < 4; b++) acc[a][b] = 0.f;
    float csum = 0.f;

    int r0 = blockIdx.x * XTX_ROWS_PER_BLK;
    int r1 = min(r0 + XTX_ROWS_PER_BLK, NPTS);

    for (int base = r0; base < r1; base += 64) {
        int nrows = r1 - base;
        if (nrows > 64) nrows = 64;
        __syncthreads();
        const float4* xg = (const float4*)(x + (long)base * C3D);
        #pragma unroll
        for (int i = 0; i < 4; i++) {
            int f4 = t + 256 * i;
            int r = f4 >> 4, k4 = f4 & 15;
            float4 v = make_float4(0.f, 0.f, 0.f, 0.f);
            if (r < nrows) v = xg[f4];
            *(float4*)(xs + r * 68 + k4 * 4) = v;
        }
        __syncthreads();
        #pragma unroll 4
        for (int r = 0; r < 64; r++) {
            float4 av = *(const float4*)(xs + r * 68 + ti * 4);
            float4 bv = *(const float4*)(xs + r * 68 + tj * 4);
            float aa[4] = {av.x, av.y, av.z, av.w};
            float bb[4] = {bv.x, bv.y, bv.z, bv.w};
            #pragma unroll
            for (int a = 0; a < 4; a++)
                #pragma unroll
                for (int b = 0; b < 4; b++) acc[a][b] += aa[a] * bb[b];
        }
        if (t < 64) {
            #pragma unroll 8
            for (int r = 0; r < 64; r++) csum += xs[r * 68 + t];
        }
    }
    #pragma unroll
    for (int a = 0; a < 4; a++)
        #pragma unroll
        for (int b = 0; b < 4; b++)
            atomic_fx(&S64[(ti * 4 + a) * 64 + tj * 4 + b], acc[a][b]);
    if (t < 64) atomic_fx(&cs64[t], csum);
}

// ---------------------------------------------------------------------------
// K3: finalize BN1 from S64/cs64 (algebraic BN-through-affine, b1 folded)
// float4 LDS reads in the 64x64 matvec
// ---------------------------------------------------------------------------
__global__ void k_finalize1(const unsigned long long* __restrict__ S64,
                            const unsigned long long* __restrict__ cs64,
                            const float* __restrict__ w1, const float* __restrict__ b1,
                            const float* __restrict__ g, const float* __restrict__ be,
                            float* __restrict__ s, float* __restrict__ sh) {
    __shared__ __align__(16) float Ss[64 * 64];
    __shared__ float cs[64];
    int t = threadIdx.x;                   // 128 threads = 128 channels
    for (int i = t; i < 4096; i += 128)
        Ss[i] = (float)((double)(long long)S64[i] * FXI);
    if (t < 64) cs[t] = (float)((double)(long long)cs64[t] * FXI);
    __syncthreads();

    float w[64];
    const float4* wg = (const float4*)(w1 + t * 64);
    #pragma unroll
    for (int k4 = 0; k4 < 16; k4++) {
        float4 wv = wg[k4];
        w[k4 * 4 + 0] = wv.x; w[k4 * 4 + 1] = wv.y;
        w[k4 * 4 + 2] = wv.z; w[k4 * 4 + 3] = wv.w;
    }
    float wc = 0.f;
    #pragma unroll
    for (int k = 0; k < 64; k++) wc += w[k] * cs[k];
    float q = 0.f;
    for (int k = 0; k < 64; k++) {
        float tk = 0.f;
        const float4* Sr = (const float4*)(Ss + k * 64);
        #pragma unroll
        for (int l4 = 0; l4 < 16; l4++) {
            float4 sv = Sr[l4];
            tk += sv.x * w[l4 * 4 + 0];
            tk += sv.y * w[l4 * 4 + 1];
            tk += sv.z * w[l4 * 4 + 2];
            tk += sv.w * w[l4 * 4 + 3];
        }
        q += w[k] * tk;
    }
    const float invN = 1.f / (float)NPTS;
    float bc = b1[t];
    float m = wc * invN + bc;
    float Eh2 = q * invN + 2.f * bc * wc * invN + bc * bc;
    float v = Eh2 - m * m;
    float sc = g[t] * rsqrtf(v + 1e-5f);
    s[t] = sc;
    sh[t] = be[t] - (wc * invN) * sc;      // (b1 - m) * sc + be
}

// ---------------------------------------------------------------------------
// K5: finalize BN2 from 16-slot u64 fixed-point sums (fixed-order reduce)
// ---------------------------------------------------------------------------
__global__ void k_finalize(const unsigned long long* __restrict__ sum64,
                           const unsigned long long* __restrict__ ssq64,
                           const float* __restrict__ g, const float* __restrict__ b,
                           float* __restrict__ s, float* __restrict__ sh) {
    int c = threadIdx.x;   // 128
    long long si = 0, qi = 0;
    for (int i = 0; i < 16; i++) {
        si += (long long)sum64[c * 16 + i];
        qi += (long long)ssq64[c * 16 + i];
    }
    float S = (float)((double)si * FXI);
    float Q = (float)((double)qi * FXI);
    const float invN = 1.f / (float)NPTS;
    float m = S * invN;
    float v = Q * invN - m * m;
    float sc = g[c] * rsqrtf(v + 1e-5f);
    s[c] = sc;
    sh[c] = b[c] - m * sc;
}

// ---------------------------------------------------------------------------
// K4: fused main kernel (MFMA bf16), 64 rows/block, 256 threads = 4 waves.
// Wave-privatized: every phase touches only rows [16*wv, 16*wv+16) except the
// final store/stats (the single __syncthreads). Same-wave LDS RAW is ordered
// by lgkmcnt fences (LDS pipe is in-order per wave).
//   A-frag (16x16x32): lane holds A[m=lane&15][k=(lane>>4)*8+j]
//   B-frag:            lane holds B[k=(lane>>4)*8+j][n=lane&15]  (row-major W)
//   D:                 m=(lane>>4)*4+reg, n=lane&15
// Gate folded through fusion GEMM by linearity:
//   out = a*(vfeat@fwA^T) + (1-a)*(ifeat@fwB^T) + fb
// LDS: single combs buffer 64x264 bf16 (33792 B) -> 4 blocks/CU.
//   cols [0,128): h, overwritten by vfeat; cols [128,256): ifeat; 8 pad.
//   Aliased at the end by outs (64x132 f32 = same 528 B/row footprint).
// ---------------------------------------------------------------------------
__global__ __launch_bounds__(256, 4) void k_main(
    const float* __restrict__ x, const int* __restrict__ coords,
    const ushort* __restrict__ img_bf, const float* __restrict__ P2,
    const ushort* __restrict__ wb,
    const float* __restrict__ bn1s, const float* __restrict__ bn1sh,
    const float* __restrict__ b2, const float* __restrict__ ab1,
    const float* __restrict__ ab2, const float* __restrict__ fb,
    float* __restrict__ out,
    unsigned long long* __restrict__ sum64, unsigned long long* __restrict__ ssq64)
{
    __shared__ __align__(16) char smem[33792];
    ushort* combs = (ushort*)smem;         // 64 x 264 bf16
    float*  outs  = (float*)smem;          // 64 x 132 f32 (same footprint)

    const ushort* w1b  = wb + WB_W1;
    const ushort* w2b  = wb + WB_W2;
    const ushort* aw1b = wb + WB_AW1;
    const ushort* aw2b = wb + WB_AW2;
    const ushort* fwb  = wb + WB_FW;

    int t = threadIdx.x;
    int n0 = blockIdx.x * 64;
    int lane = t & 63, wv = t >> 6;
    int l15 = lane & 15, lq = lane >> 4;
    int m0 = wv * 16;

    // ---- P1a: issue GEMM1 A-operand loads (direct from global x) ----
    const float* xr = x + (long)(n0 + m0 + l15) * C3D;
    float4 xa0 = *(const float4*)(xr + lq * 8);
    float4 xa1 = *(const float4*)(xr + lq * 8 + 4);
    float4 xb0 = *(const float4*)(xr + 32 + lq * 8);
    float4 xb1 = *(const float4*)(xr + 32 + lq * 8 + 4);

    // ---- P1b: projection, per-lane (row = m0 + (lane>>2), 4x redundant) ----
    int grow = m0 + (lane >> 2);
    int qc = lane & 3;
    int poff_[4]; float pwgt_[4];
    {
        int4 cd = *(const int4*)(coords + (long)(n0 + grow) * 4);
        int b = cd.x;
        float p0 = (float)cd.y * 0.05f;
        float p1 = (float)cd.z * 0.05f - 40.f;
        float p2 = (float)cd.w * 0.1f - 3.f;
        const float* P = P2 + b * 12;
        float cam0 = P[0] * p0 + P[1] * p1 + P[2]  * p2 + P[3];
        float cam1 = P[4] * p0 + P[5] * p1 + P[6]  * p2 + P[7];
        float cam2 = P[8] * p0 + P[9] * p1 + P[10] * p2 + P[11];
        float d = cam2 + 1e-8f;
        float px = cam0 / d, py = cam1 / d;
        float gx = fminf(fmaxf(px / (float)WW * 2.f - 1.f, -1.f), 1.f);
        float gy = fminf(fmaxf(py / (float)HH * 2.f - 1.f, -1.f), 1.f);
        float ix = ((gx + 1.f) * (float)WW - 1.f) * 0.5f;
        float iy = ((gy + 1.f) * (float)HH - 1.f) * 0.5f;
        float x0f = floorf(ix), y0f = floorf(iy);
        float wx = ix - x0f, wy = iy - y0f;
        int x0 = (int)x0f, y0 = (int)y0f;
        #pragma unroll
        for (int j = 0; j < 4; j++) {
            int xc = x0 + (j & 1), yc = y0 + (j >> 1);
            float wgt = ((j & 1) ? wx : 1.f - wx) * ((j >> 1) ? wy : 1.f - wy);
            bool valid = (xc >= 0) && (xc < WW) && (yc >= 0) && (yc < HH);
            int xcc = min(max(xc, 0), WW - 1), ycc = min(max(yc, 0), HH - 1);
            poff_[j] = ((b * HH + ycc) * WW + xcc) * C2D;
            pwgt_[j] = valid ? wgt : 0.f;
        }
    }

    // ---- P1c: bilinear gather -> combs[grow, 128 + qc*32 ..) (wave-local) ----
    {
        float gacc[32];
        #pragma unroll
        for (int i = 0; i < 32; i++) gacc[i] = 0.f;
        #pragma unroll
        for (int j = 0; j < 4; j++) {
            float wgt = pwgt_[j];
            const s16x8* src = (const s16x8*)(img_bf + poff_[j] + qc * 32);
            #pragma unroll
            for (int q = 0; q < 4; q++) {
                s16x8 v = src[q];
                #pragma unroll
                for (int e = 0; e < 8; e++)
                    gacc[q * 8 + e] += wgt * bf2f((ushort)v[e]);
            }
        }
        #pragma unroll
        for (int g = 0; g < 4; g++) {
            s16x8 v;
            #pragma unroll
            for (int e = 0; e < 8; e++) v[e] = (short)f2bf(gacc[g * 8 + e]);
            *(s16x8*)(combs + grow * 264 + 128 + qc * 32 + g * 8) = v;
        }
    }

    // ---- P1d: GEMM1 (K=64) + BN1 + relu -> combs[:, 0:128) (h) ----
    {
        s16x8 af0 = pack_bf8(xa0, xa1);
        s16x8 af1 = pack_bf8(xb0, xb1);
        #pragma unroll
        for (int nt = 0; nt < 8; nt++) {
            f32x4 acc = {0.f, 0.f, 0.f, 0.f};
            s16x8 bf0 = *(const s16x8*)(w1b + (nt * 16 + l15) * 64 + lq * 8);
            s16x8 bf1 = *(const s16x8*)(w1b + (nt * 16 + l15) * 64 + 32 + lq * 8);
            acc = __builtin_amdgcn_mfma_f32_16x16x32_bf16(af0, bf0, acc, 0, 0, 0);
            acc = __builtin_amdgcn_mfma_f32_16x16x32_bf16(af1, bf1, acc, 0, 0, 0);
            int c = nt * 16 + l15;
            float sc = bn1s[c], shf = bn1sh[c];
            #pragma unroll
            for (int r = 0; r < 4; r++)
                combs[(m0 + lq * 4 + r) * 264 + c] = f2bf(fmaxf(acc[r] * sc + shf, 0.f));
        }
    }
    WAVE_LDS_FENCE();

    // ---- P2: GEMM2 (K=128) + b2 -> vfeat, overwriting h in place ----
    {
        s16x8 af2[4];
        #pragma unroll
        for (int s = 0; s < 4; s++)
            af2[s] = *(const s16x8*)(combs + (m0 + l15) * 264 + s * 32 + lq * 8);
        WAVE_LDS_FENCE();   // reads landed in regs before same-address writes
        #pragma unroll
        for (int nt = 0; nt < 8; nt++) {
            f32x4 acc = {0.f, 0.f, 0.f, 0.f};
            #pragma unroll
            for (int s = 0; s < 4; s++) {
                s16x8 bf = *(const s16x8*)(w2b + (nt * 16 + l15) * 128 + s * 32 + lq * 8);
                acc = __builtin_amdgcn_mfma_f32_16x16x32_bf16(af2[s], bf, acc, 0, 0, 0);
            }
            int c = nt * 16 + l15;
            float bb = b2[c];
            #pragma unroll
            for (int r = 0; r < 4; r++)
                combs[(m0 + lq * 4 + r) * 264 + c] = f2bf(acc[r] + bb);
        }
    }
    WAVE_LDS_FENCE();

    // ---- P3: load comb fragments once (K=256), shared by att1 and fusion ----
    s16x8 af[8];
    #pragma unroll
    for (int s = 0; s < 8; s++)
        af[s] = *(const s16x8*)(combs + (m0 + l15) * 264 + s * 32 + lq * 8);

    // ---- P4: att1 (MFMA) + att2 (per-lane dot + shfl_xor reduce) ----
    float aatt[4];
    {
        float satt[4] = {0.f, 0.f, 0.f, 0.f};
        #pragma unroll
        for (int nt = 0; nt < 8; nt++) {
            f32x4 acc = {0.f, 0.f, 0.f, 0.f};
            #pragma unroll
            for (int s = 0; s < 8; s++) {
                s16x8 bf = *(const s16x8*)(aw1b + (nt * 16 + l15) * 256 + s * 32 + lq * 8);
                acc = __builtin_amdgcn_mfma_f32_16x16x32_bf16(af[s], bf, acc, 0, 0, 0);
            }
            int c = nt * 16 + l15;
            float bb = ab1[c];
            float w2c = bf2f(aw2b[c]);
            #pragma unroll
            for (int r = 0; r < 4; r++)
                satt[r] += fmaxf(acc[r] + bb, 0.f) * w2c;
        }
        #pragma unroll
        for (int d = 1; d < 16; d <<= 1) {
            #pragma unroll
            for (int r = 0; r < 4; r++)
                satt[r] += __shfl_xor(satt[r], d, 64);
        }
        float z0 = ab2[0];
        #pragma unroll
        for (int r = 0; r < 4; r++)
            aatt[r] = 1.f / (1.f + expf(-(satt[r] + z0)));
    }

    // ---- P5: fusion GEMM, gate folded: out = a*f1 + (1-a)*f2 + fb ----
    #pragma unroll
    for (int nt = 0; nt < 8; nt++) {
        f32x4 f1 = {0.f, 0.f, 0.f, 0.f};
        f32x4 f2 = {0.f, 0.f, 0.f, 0.f};
        #pragma unroll
        for (int s = 0; s < 4; s++) {
            s16x8 bf = *(const s16x8*)(fwb + (nt * 16 + l15) * 256 + s * 32 + lq * 8);
            f1 = __builtin_amdgcn_mfma_f32_16x16x32_bf16(af[s], bf, f1, 0, 0, 0);
        }
        #pragma unroll
        for (int s = 4; s < 8; s++) {
            s16x8 bf = *(const s16x8*)(fwb + (nt * 16 + l15) * 256 + s * 32 + lq * 8);
            f2 = __builtin_amdgcn_mfma_f32_16x16x32_bf16(af[s], bf, f2, 0, 0, 0);
        }
        int c = nt * 16 + l15;
        float bb = fb[c];
        #pragma unroll
        for (int r = 0; r < 4; r++)
            outs[(m0 + lq * 4 + r) * 132 + c] =
                aatt[r] * f1[r] + (1.f - aatt[r]) * f2[r] + bb;
    }

    __syncthreads();   // the ONLY cross-wave barrier

    // ---- P6: coalesced global store + BN2 stats (fixed-point u64) ----
    {
        float4* og = (float4*)(out + (long)n0 * OUTC);
        #pragma unroll
        for (int i = 0; i < 8; i++) {
            int f4 = t + 256 * i;              // 2048 float4 = 64 rows x 32
            int row = f4 >> 5, c4 = f4 & 31;
            float4 v = *(const float4*)(outs + row * 132 + c4 * 4);
            og[row * 32 + c4] = v;
        }
        int slot = blockIdx.x & 15;
        if (t < 128) {
            float S = 0.f;
            #pragma unroll 8
            for (int row = 0; row < 64; row++) S += outs[row * 132 + t];
            atomic_fx(&sum64[t * 16 + slot], S);
        } else {
            int c = t - 128;
            float Q = 0.f;
            #pragma unroll 8
            for (int row = 0; row < 64; row++) { float v = outs[row * 132 + c]; Q += v * v; }
            atomic_fx(&ssq64[c * 16 + slot], Q);
        }
    }
}

// ---------------------------------------------------------------------------
// K6: in-place BN2 + relu on d_out
// ---------------------------------------------------------------------------
__global__ __launch_bounds__(256) void k_bnf(float* __restrict__ out,
                                             const float* __restrict__ s,
                                             const float* __restrict__ sh) {
    long i = (long)blockIdx.x * 256 + threadIdx.x;   // over 6.4M float4
    float4* p = (float4*)out;
    float4 v = p[i];
    int c4 = (int)(i & 31);
    float4 sv  = ((const float4*)s)[c4];
    float4 shv = ((const float4*)sh)[c4];
    v.x = fmaxf(v.x * sv.x + shv.x, 0.f);
    v.y = fmaxf(v.y * sv.y + shv.y, 0.f);
    v.z = fmaxf(v.z * sv.z + shv.z, 0.f);
    v.w = fmaxf(v.w * sv.w + shv.w, 0.f);
    p[i] = v;
}

// ---------------------------------------------------------------------------
extern "C" void kernel_launch(void* const* d_in, const int* in_sizes, int n_in,
                              void* d_out, int out_size, void* d_ws, size_t ws_size,
                              hipStream_t stream) {
    const float* x      = (const float*)d_in[0];
    const int*   coords = (const int*)d_in[1];
    const float* img    = (const float*)d_in[2];
    const float* P2     = (const float*)d_in[3];
    const float* w1     = (const float*)d_in[4];
    const float* b1     = (const float*)d_in[5];
    const float* g1     = (const float*)d_in[6];
    const float* be1    = (const float*)d_in[7];
    const float* w2     = (const float*)d_in[8];
    const float* b2     = (const float*)d_in[9];
    const float* aw1    = (const float*)d_in[10];
    const float* ab1    = (const float*)d_in[11];
    const float* aw2    = (const float*)d_in[12];
    const float* ab2    = (const float*)d_in[13];
    const float* fw     = (const float*)d_in[14];
    const float* fb     = (const float*)d_in[15];
    const float* gf     = (const float*)d_in[16];
    const float* bef    = (const float*)d_in[17];
    float* out = (float*)d_out;

    float* wsf = (float*)d_ws;
    ushort* wb = (ushort*)wsf;                                   // 90240 ushorts
    unsigned long long* S64   = (unsigned long long*)(wsf + WS_S64);
    unsigned long long* cs64  = (unsigned long long*)(wsf + WS_CS64);
    unsigned long long* sum64 = (unsigned long long*)(wsf + WS_SUM64);
    unsigned long long* ssq64 = (unsigned long long*)(wsf + WS_SSQ64);
    float* zero_base = wsf + WS_S64;
    float* s1  = wsf + WS_DERIV;
    float* sh1 = s1 + 128;
    float* s2  = sh1 + 128;
    float* sh2 = s2 + 128;
    ushort* img_bf = (ushort*)(wsf + WS_IMG);                    // 15,335,424 ushorts

    // K1: transpose image (bf16) + zero stats region
    k_transpose<<<BB * HH * 10 * 4, 256, 0, stream>>>(img, img_bf, zero_base);
    // K1b: bf16 weights
    k_prepw<<<(WB_TOTAL + 255) / 256, 256, 0, stream>>>(w1, w2, aw1, aw2, fw, wb);
    // K2: X^T X + colsum (u64 fixed-point atomics, deterministic)
    k_xtx<<<XTX_BLOCKS, 256, 0, stream>>>(x, S64, cs64);
    // K3: finalize BN1 (algebraic, b1 folded)
    k_finalize1<<<1, 128, 0, stream>>>(S64, cs64, w1, b1, g1, be1, s1, sh1);
    // K4: fused main (MFMA), 3125 blocks, 1 barrier, 4 blocks/CU
    k_main<<<NPTS / 64, 256, 0, stream>>>(x, coords, img_bf, P2, wb, s1, sh1,
                                          b2, ab1, ab2, fb, out, sum64, ssq64);
    // K5: finalize BN2 (fixed-order slot reduce)
    k_finalize<<<1, 128, 0, stream>>>(sum64, ssq64, gf, bef, s2, sh2);
    // K6: in-place BN2 + relu
    k_bnf<<<NPTS * OUTC / 4 / 256, 256, 0, stream>>>(out, s2, sh2);
}

// Round 3
// 761.406 us; speedup vs baseline: 1.0041x; 1.0041x over previous
//
#include <hip/hip_runtime.h>
#include <hip/hip_bf16.h>

// Problem constants (match reference)
#define NPTS 200000
#define BB   4
#define C3D  64
#define C2D  128
#define HH   96
#define WW   312
#define MID  128
#define OUTC 128

// bf16 weight sub-offsets (ushort elements)
#define WB_W1   0
#define WB_W2   8192
#define WB_AW1  24576
#define WB_AW2  57344
#define WB_FW   57472
#define WB_TOTAL 90240                     // ushorts = 45120 floats

// Fixed-point scale for deterministic integer atomics
#define FXS 1048576.0f
#define FXI (1.0 / 1048576.0)

// ws layout (float offsets). All stats are u64 fixed-point (2 floats each).
#define WS_S64    45120                    // 4096 u64  -> 8192 floats
#define WS_CS64   53312                    // 64 u64    -> 128 floats
#define WS_SUM64  53440                    // 128*16 u64-> 4096 floats
#define WS_SSQ64  57536                    // 128*16 u64-> 4096 floats
#define ZERO_N    16512                    // floats to zero: 45120..61632
#define WS_DERIV  61632                    // s1,sh1,s2,sh2 : 512
#define WS_IMG    62144                    // bf16 image, 15,335,424 ushorts

typedef __attribute__((ext_vector_type(8))) short s16x8;
typedef __attribute__((ext_vector_type(4))) float f32x4;

__device__ __forceinline__ ushort f2bf(float f) {
    unsigned u = __float_as_uint(f);
    unsigned r = (u + 0x7FFFu + ((u >> 16) & 1u)) >> 16;   // RNE
    return (ushort)r;
}
__device__ __forceinline__ float bf2f(ushort u) {
    return __uint_as_float(((unsigned)u) << 16);
}
__device__ __forceinline__ void atomic_fx(unsigned long long* p, float v) {
    atomicAdd(p, (unsigned long long)(long long)llrintf(v * FXS));
}
__device__ __forceinline__ s16x8 pack_bf8(float4 a, float4 b) {
    s16x8 v;
    v[0] = (short)f2bf(a.x); v[1] = (short)f2bf(a.y);
    v[2] = (short)f2bf(a.z); v[3] = (short)f2bf(a.w);
    v[4] = (short)f2bf(b.x); v[5] = (short)f2bf(b.y);
    v[6] = (short)f2bf(b.z); v[7] = (short)f2bf(b.w);
    return v;
}
// Same-wave LDS write->read ordering: drain lgkm, block compiler motion.
#define WAVE_LDS_FENCE() do { \
    asm volatile("s_waitcnt lgkmcnt(0)" ::: "memory"); \
    __builtin_amdgcn_sched_barrier(0); \
} while (0)

// ---------------------------------------------------------------------------
// K1: transpose image (B,C,H,W) -> (B,H,W,C) bf16, and zero the stats region
// ---------------------------------------------------------------------------
__global__ __launch_bounds__(256) void k_transpose(const float* __restrict__ img,
                                                   ushort* __restrict__ img_bf,
                                                   float* __restrict__ stats) {
    __shared__ float tile[32][33];
    int flat = blockIdx.x * 256 + threadIdx.x;
    if (flat < ZERO_N) stats[flat] = 0.f;

    int bid = blockIdx.x;
    int ct = bid & 3;  bid >>= 2;          // 4 channel tiles
    int wt = bid % 10; bid /= 10;          // 10 width tiles
    int h  = bid % HH;
    int b  = bid / HH;
    int tx = threadIdx.x & 31, ty = threadIdx.x >> 5;   // 32 x 8
    int w0 = wt * 32, c0 = ct * 32;

    #pragma unroll
    for (int i = 0; i < 4; i++) {
        int c = c0 + ty + 8 * i;
        int w = w0 + tx;
        float v = 0.f;
        if (w < WW) v = img[((b * C2D + c) * HH + h) * WW + w];
        tile[ty + 8 * i][tx] = v;
    }
    __syncthreads();
    #pragma unroll
    for (int i = 0; i < 4; i++) {
        int w = w0 + ty + 8 * i;
        int c = c0 + tx;
        if (w < WW) img_bf[((b * HH + h) * WW + w) * C2D + c] = f2bf(tile[tx][ty + 8 * i]);
    }
}

// ---------------------------------------------------------------------------
// K1b: convert weights to bf16 (row-major unchanged)
// ---------------------------------------------------------------------------
__global__ __launch_bounds__(256) void k_prepw(const float* __restrict__ w1,
                                               const float* __restrict__ w2,
                                               const float* __restrict__ aw1,
                                               const float* __restrict__ aw2,
                                               const float* __restrict__ fw,
                                               ushort* __restrict__ wb) {
    int i = blockIdx.x * 256 + threadIdx.x;
    if (i >= WB_TOTAL) return;
    float v;
    if      (i < WB_W2)  v = w1[i - WB_W1];
    else if (i < WB_AW1) v = w2[i - WB_W2];
    else if (i < WB_AW2) v = aw1[i - WB_AW1];
    else if (i < WB_FW)  v = aw2[i - WB_AW2];
    else                 v = fw[i - WB_FW];
    wb[i] = f2bf(v);
}

// ---------------------------------------------------------------------------
// K2: X^T X (64x64) + colsum, fixed-point u64 atomics (deterministic)
// ---------------------------------------------------------------------------
#define XTX_ROWS_PER_BLK 256
#define XTX_BLOCKS ((NPTS + XTX_ROWS_PER_BLK - 1) / XTX_ROWS_PER_BLK)   // 782

__global__ __launch_bounds__(256) void k_xtx(const float* __restrict__ x,
                                             unsigned long long* __restrict__ S64,
                                             unsigned long long* __restrict__ cs64) {
    __shared__ float xs[64 * 68];
    int t = threadIdx.x;
    int ti = t >> 4, tj = t & 15;
    float acc[4][4];
    #pragma unroll
    for (int a = 0; a < 4; a++)
        #pragma unroll
        for (int b = 0; b < 4; b++) acc[a][b] = 0.f;
    float csum = 0.f;

    int r0 = blockIdx.x * XTX_ROWS_PER_BLK;
    int r1 = min(r0 + XTX_ROWS_PER_BLK, NPTS);

    for (int base = r0; base < r1; base += 64) {
        int nrows = r1 - base;
        if (nrows > 64) nrows = 64;
        __syncthreads();
        const float4* xg = (const float4*)(x + (long)base * C3D);
        #pragma unroll
        for (int i = 0; i < 4; i++) {
            int f4 = t + 256 * i;
            int r = f4 >> 4, k4 = f4 & 15;
            float4 v = make_float4(0.f, 0.f, 0.f, 0.f);
            if (r < nrows) v = xg[f4];
            *(float4*)(xs + r * 68 + k4 * 4) = v;
        }
        __syncthreads();
        #pragma unroll 4
        for (int r = 0; r < 64; r++) {
            float4 av = *(const float4*)(xs + r * 68 + ti * 4);
            float4 bv = *(const float4*)(xs + r * 68 + tj * 4);
            float aa[4] = {av.x, av.y, av.z, av.w};
            float bb[4] = {bv.x, bv.y, bv.z, bv.w};
            #pragma unroll
            for (int a = 0; a < 4; a++)
                #pragma unroll
                for (int b = 0; b < 4; b++) acc[a][b] += aa[a] * bb[b];
        }
        if (t < 64) {
            #pragma unroll 8
            for (int r = 0; r < 64; r++) csum += xs[r * 68 + t];
        }
    }
    #pragma unroll
    for (int a = 0; a < 4; a++)
        #pragma unroll
        for (int b = 0; b < 4; b++)
            atomic_fx(&S64[(ti * 4 + a) * 64 + tj * 4 + b], acc[a][b]);
    if (t < 64) atomic_fx(&cs64[t], csum);
}

// ---------------------------------------------------------------------------
// K3: finalize BN1 from S64/cs64 (algebraic BN-through-affine, b1 folded)
// ---------------------------------------------------------------------------
__global__ void k_finalize1(const unsigned long long* __restrict__ S64,
                            const unsigned long long* __restrict__ cs64,
                            const float* __restrict__ w1, const float* __restrict__ b1,
                            const float* __restrict__ g, const float* __restrict__ be,
                            float* __restrict__ s, float* __restrict__ sh) {
    __shared__ __align__(16) float Ss[64 * 64];
    __shared__ float cs[64];
    int t = threadIdx.x;                   // 128 threads = 128 channels
    for (int i = t; i < 4096; i += 128)
        Ss[i] = (float)((double)(long long)S64[i] * FXI);
    if (t < 64) cs[t] = (float)((double)(long long)cs64[t] * FXI);
    __syncthreads();

    float w[64];
    const float4* wg = (const float4*)(w1 + t * 64);
    #pragma unroll
    for (int k4 = 0; k4 < 16; k4++) {
        float4 wv = wg[k4];
        w[k4 * 4 + 0] = wv.x; w[k4 * 4 + 1] = wv.y;
        w[k4 * 4 + 2] = wv.z; w[k4 * 4 + 3] = wv.w;
    }
    float wc = 0.f;
    #pragma unroll
    for (int k = 0; k < 64; k++) wc += w[k] * cs[k];
    float q = 0.f;
    for (int k = 0; k < 64; k++) {
        float tk = 0.f;
        const float4* Sr = (const float4*)(Ss + k * 64);
        #pragma unroll
        for (int l4 = 0; l4 < 16; l4++) {
            float4 sv = Sr[l4];
            tk += sv.x * w[l4 * 4 + 0];
            tk += sv.y * w[l4 * 4 + 1];
            tk += sv.z * w[l4 * 4 + 2];
            tk += sv.w * w[l4 * 4 + 3];
        }
        q += w[k] * tk;
    }
    const float invN = 1.f / (float)NPTS;
    float bc = b1[t];
    float m = wc * invN + bc;
    float Eh2 = q * invN + 2.f * bc * wc * invN + bc * bc;
    float v = Eh2 - m * m;
    float sc = g[t] * rsqrtf(v + 1e-5f);
    s[t] = sc;
    sh[t] = be[t] - (wc * invN) * sc;      // (b1 - m) * sc + be
}

// ---------------------------------------------------------------------------
// K5: finalize BN2 from 16-slot u64 fixed-point sums (fixed-order reduce)
// ---------------------------------------------------------------------------
__global__ void k_finalize(const unsigned long long* __restrict__ sum64,
                           const unsigned long long* __restrict__ ssq64,
                           const float* __restrict__ g, const float* __restrict__ b,
                           float* __restrict__ s, float* __restrict__ sh) {
    int c = threadIdx.x;   // 128
    long long si = 0, qi = 0;
    for (int i = 0; i < 16; i++) {
        si += (long long)sum64[c * 16 + i];
        qi += (long long)ssq64[c * 16 + i];
    }
    float S = (float)((double)si * FXI);
    float Q = (float)((double)qi * FXI);
    const float invN = 1.f / (float)NPTS;
    float m = S * invN;
    float v = Q * invN - m * m;
    float sc = g[c] * rsqrtf(v + 1e-5f);
    s[c] = sc;
    sh[c] = b[c] - m * sc;
}

// ---------------------------------------------------------------------------
// K4: fused main kernel (MFMA bf16), 64 rows/block, 256 threads = 4 waves.
// Wave-privatized, single cross-wave barrier (see round-2 notes).
// Register-pressure discipline (round-3 fix for the spill round 2 exposed:
// +204 MB scratch traffic, VGPR 64):
//   - gather processes ONE 8-channel group at a time (8 accumulators, not 32)
//   - x float4s are packed to bf16 fragments immediately (16 regs -> 8)
//   - amdgpu_waves_per_eu(4,4): allocator gets the full 128-VGPR budget and
//     cannot chase 8 waves/EU by spilling (LDS caps at 4 blocks/CU anyway).
// ---------------------------------------------------------------------------
__global__ __launch_bounds__(256)
__attribute__((amdgpu_waves_per_eu(4, 4)))
void k_main(
    const float* __restrict__ x, const int* __restrict__ coords,
    const ushort* __restrict__ img_bf, const float* __restrict__ P2,
    const ushort* __restrict__ wb,
    const float* __restrict__ bn1s, const float* __restrict__ bn1sh,
    const float* __restrict__ b2, const float* __restrict__ ab1,
    const float* __restrict__ ab2, const float* __restrict__ fb,
    float* __restrict__ out,
    unsigned long long* __restrict__ sum64, unsigned long long* __restrict__ ssq64)
{
    __shared__ __align__(16) char smem[33792];
    ushort* combs = (ushort*)smem;         // 64 x 264 bf16
    float*  outs  = (float*)smem;          // 64 x 132 f32 (same footprint)

    const ushort* w1b  = wb + WB_W1;
    const ushort* w2b  = wb + WB_W2;
    const ushort* aw1b = wb + WB_AW1;
    const ushort* aw2b = wb + WB_AW2;
    const ushort* fwb  = wb + WB_FW;

    int t = threadIdx.x;
    int n0 = blockIdx.x * 64;
    int lane = t & 63, wv = t >> 6;
    int l15 = lane & 15, lq = lane >> 4;
    int m0 = wv * 16;

    // ---- P1a: GEMM1 A-operand: load from global, pack to bf16 immediately ----
    s16x8 af0, af1;
    {
        const float* xr = x + (long)(n0 + m0 + l15) * C3D;
        float4 xa0 = *(const float4*)(xr + lq * 8);
        float4 xa1 = *(const float4*)(xr + lq * 8 + 4);
        float4 xb0 = *(const float4*)(xr + 32 + lq * 8);
        float4 xb1 = *(const float4*)(xr + 32 + lq * 8 + 4);
        af0 = pack_bf8(xa0, xa1);
        af1 = pack_bf8(xb0, xb1);
    }

    // ---- P1b: projection, per-lane (row = m0 + (lane>>2), 4x redundant) ----
    int grow = m0 + (lane >> 2);
    int qc = lane & 3;
    int poff_[4]; float pwgt_[4];
    {
        int4 cd = *(const int4*)(coords + (long)(n0 + grow) * 4);
        int b = cd.x;
        float p0 = (float)cd.y * 0.05f;
        float p1 = (float)cd.z * 0.05f - 40.f;
        float p2 = (float)cd.w * 0.1f - 3.f;
        const float* P = P2 + b * 12;
        float cam0 = P[0] * p0 + P[1] * p1 + P[2]  * p2 + P[3];
        float cam1 = P[4] * p0 + P[5] * p1 + P[6]  * p2 + P[7];
        float cam2 = P[8] * p0 + P[9] * p1 + P[10] * p2 + P[11];
        float d = cam2 + 1e-8f;
        float px = cam0 / d, py = cam1 / d;
        float gx = fminf(fmaxf(px / (float)WW * 2.f - 1.f, -1.f), 1.f);
        float gy = fminf(fmaxf(py / (float)HH * 2.f - 1.f, -1.f), 1.f);
        float ix = ((gx + 1.f) * (float)WW - 1.f) * 0.5f;
        float iy = ((gy + 1.f) * (float)HH - 1.f) * 0.5f;
        float x0f = floorf(ix), y0f = floorf(iy);
        float wx = ix - x0f, wy = iy - y0f;
        int x0 = (int)x0f, y0 = (int)y0f;
        #pragma unroll
        for (int j = 0; j < 4; j++) {
            int xc = x0 + (j & 1), yc = y0 + (j >> 1);
            float wgt = ((j & 1) ? wx : 1.f - wx) * ((j >> 1) ? wy : 1.f - wy);
            bool valid = (xc >= 0) && (xc < WW) && (yc >= 0) && (yc < HH);
            int xcc = min(max(xc, 0), WW - 1), ycc = min(max(yc, 0), HH - 1);
            poff_[j] = ((b * HH + ycc) * WW + xcc) * C2D;
            pwgt_[j] = valid ? wgt : 0.f;
        }
    }

    // ---- P1c: bilinear gather, ONE 8-channel group at a time (8 accs) ----
    #pragma unroll
    for (int g = 0; g < 4; g++) {
        float a8[8];
        #pragma unroll
        for (int e = 0; e < 8; e++) a8[e] = 0.f;
        #pragma unroll
        for (int j = 0; j < 4; j++) {
            s16x8 v = *(const s16x8*)(img_bf + poff_[j] + qc * 32 + g * 8);
            float wgt = pwgt_[j];
            #pragma unroll
            for (int e = 0; e < 8; e++)
                a8[e] += wgt * bf2f((ushort)v[e]);
        }
        s16x8 o;
        #pragma unroll
        for (int e = 0; e < 8; e++) o[e] = (short)f2bf(a8[e]);
        *(s16x8*)(combs + grow * 264 + 128 + qc * 32 + g * 8) = o;
    }

    // ---- P1d: GEMM1 (K=64) + BN1 + relu -> combs[:, 0:128) (h) ----
    #pragma unroll
    for (int nt = 0; nt < 8; nt++) {
        f32x4 acc = {0.f, 0.f, 0.f, 0.f};
        s16x8 bf0 = *(const s16x8*)(w1b + (nt * 16 + l15) * 64 + lq * 8);
        s16x8 bf1 = *(const s16x8*)(w1b + (nt * 16 + l15) * 64 + 32 + lq * 8);
        acc = __builtin_amdgcn_mfma_f32_16x16x32_bf16(af0, bf0, acc, 0, 0, 0);
        acc = __builtin_amdgcn_mfma_f32_16x16x32_bf16(af1, bf1, acc, 0, 0, 0);
        int c = nt * 16 + l15;
        float sc = bn1s[c], shf = bn1sh[c];
        #pragma unroll
        for (int r = 0; r < 4; r++)
            combs[(m0 + lq * 4 + r) * 264 + c] = f2bf(fmaxf(acc[r] * sc + shf, 0.f));
    }
    WAVE_LDS_FENCE();

    // ---- P2: GEMM2 (K=128) + b2 -> vfeat, overwriting h in place ----
    {
        s16x8 af2[4];
        #pragma unroll
        for (int s = 0; s < 4; s++)
            af2[s] = *(const s16x8*)(combs + (m0 + l15) * 264 + s * 32 + lq * 8);
        WAVE_LDS_FENCE();   // reads landed in regs before same-address writes
        #pragma unroll
        for (int nt = 0; nt < 8; nt++) {
            f32x4 acc = {0.f, 0.f, 0.f, 0.f};
            #pragma unroll
            for (int s = 0; s < 4; s++) {
                s16x8 bf = *(const s16x8*)(w2b + (nt * 16 + l15) * 128 + s * 32 + lq * 8);
                acc = __builtin_amdgcn_mfma_f32_16x16x32_bf16(af2[s], bf, acc, 0, 0, 0);
            }
            int c = nt * 16 + l15;
            float bb = b2[c];
            #pragma unroll
            for (int r = 0; r < 4; r++)
                combs[(m0 + lq * 4 + r) * 264 + c] = f2bf(acc[r] + bb);
        }
    }
    WAVE_LDS_FENCE();

    // ---- P3: load comb fragments once (K=256), shared by att1 and fusion ----
    s16x8 af[8];
    #pragma unroll
    for (int s = 0; s < 8; s++)
        af[s] = *(const s16x8*)(combs + (m0 + l15) * 264 + s * 32 + lq * 8);

    // ---- P4: att1 (MFMA) + att2 (per-lane dot + shfl_xor reduce) ----
    float aatt[4];
    {
        float satt[4] = {0.f, 0.f, 0.f, 0.f};
        #pragma unroll
        for (int nt = 0; nt < 8; nt++) {
            f32x4 acc = {0.f, 0.f, 0.f, 0.f};
            #pragma unroll
            for (int s = 0; s < 8; s++) {
                s16x8 bf = *(const s16x8*)(aw1b + (nt * 16 + l15) * 256 + s * 32 + lq * 8);
                acc = __builtin_amdgcn_mfma_f32_16x16x32_bf16(af[s], bf, acc, 0, 0, 0);
            }
            int c = nt * 16 + l15;
            float bb = ab1[c];
            float w2c = bf2f(aw2b[c]);
            #pragma unroll
            for (int r = 0; r < 4; r++)
                satt[r] += fmaxf(acc[r] + bb, 0.f) * w2c;
        }
        #pragma unroll
        for (int d = 1; d < 16; d <<= 1) {
            #pragma unroll
            for (int r = 0; r < 4; r++)
                satt[r] += __shfl_xor(satt[r], d, 64);
        }
        float z0 = ab2[0];
        #pragma unroll
        for (int r = 0; r < 4; r++)
            aatt[r] = 1.f / (1.f + expf(-(satt[r] + z0)));
    }

    // ---- P5: fusion GEMM, gate folded: out = a*f1 + (1-a)*f2 + fb ----
    #pragma unroll
    for (int nt = 0; nt < 8; nt++) {
        f32x4 f1 = {0.f, 0.f, 0.f, 0.f};
        f32x4 f2 = {0.f, 0.f, 0.f, 0.f};
        #pragma unroll
        for (int s = 0; s < 4; s++) {
            s16x8 bf = *(const s16x8*)(fwb + (nt * 16 + l15) * 256 + s * 32 + lq * 8);
            f1 = __builtin_amdgcn_mfma_f32_16x16x32_bf16(af[s], bf, f1, 0, 0, 0);
        }
        #pragma unroll
        for (int s = 4; s < 8; s++) {
            s16x8 bf = *(const s16x8*)(fwb + (nt * 16 + l15) * 256 + s * 32 + lq * 8);
            f2 = __builtin_amdgcn_mfma_f32_16x16x32_bf16(af[s], bf, f2, 0, 0, 0);
        }
        int c = nt * 16 + l15;
        float bb = fb[c];
        #pragma unroll
        for (int r = 0; r < 4; r++)
            outs[(m0 + lq * 4 + r) * 132 + c] =
                aatt[r] * f1[r] + (1.f - aatt[r]) * f2[r] + bb;
    }

    __syncthreads();   // the ONLY cross-wave barrier

    // ---- P6: coalesced global store + BN2 stats (fixed-point u64) ----
    {
        float4* og = (float4*)(out + (long)n0 * OUTC);
        #pragma unroll
        for (int i = 0; i < 8; i++) {
            int f4 = t + 256 * i;              // 2048 float4 = 64 rows x 32
            int row = f4 >> 5, c4 = f4 & 31;
            float4 v = *(const float4*)(outs + row * 132 + c4 * 4);
            og[row * 32 + c4] = v;
        }
        int slot = blockIdx.x & 15;
        if (t < 128) {
            float S = 0.f;
            #pragma unroll 8
            for (int row = 0; row < 64; row++) S += outs[row * 132 + t];
            atomic_fx(&sum64[t * 16 + slot], S);
        } else {
            int c = t - 128;
            float Q = 0.f;
            #pragma unroll 8
            for (int row = 0; row < 64; row++) { float v = outs[row * 132 + c]; Q += v * v; }
            atomic_fx(&ssq64[c * 16 + slot], Q);
        }
    }
}

// ---------------------------------------------------------------------------
// K6: in-place BN2 + relu on d_out
// ---------------------------------------------------------------------------
__global__ __launch_bounds__(256) void k_bnf(float* __restrict__ out,
                                             const float* __restrict__ s,
                                             const float* __restrict__ sh) {
    long i = (long)blockIdx.x * 256 + threadIdx.x;   // over 6.4M float4
    float4* p = (float4*)out;
    float4 v = p[i];
    int c4 = (int)(i & 31);
    float4 sv  = ((const float4*)s)[c4];
    float4 shv = ((const float4*)sh)[c4];
    v.x = fmaxf(v.x * sv.x + shv.x, 0.f);
    v.y = fmaxf(v.y * sv.y + shv.y, 0.f);
    v.z = fmaxf(v.z * sv.z + shv.z, 0.f);
    v.w = fmaxf(v.w * sv.w + shv.w, 0.f);
    p[i] = v;
}

// ---------------------------------------------------------------------------
extern "C" void kernel_launch(void* const* d_in, const int* in_sizes, int n_in,
                              void* d_out, int out_size, void* d_ws, size_t ws_size,
                              hipStream_t stream) {
    const float* x      = (const float*)d_in[0];
    const int*   coords = (const int*)d_in[1];
    const float* img    = (const float*)d_in[2];
    const float* P2     = (const float*)d_in[3];
    const float* w1     = (const float*)d_in[4];
    const float* b1     = (const float*)d_in[5];
    const float* g1     = (const float*)d_in[6];
    const float* be1    = (const float*)d_in[7];
    const float* w2     = (const float*)d_in[8];
    const float* b2     = (const float*)d_in[9];
    const float* aw1    = (const float*)d_in[10];
    const float* ab1    = (const float*)d_in[11];
    const float* aw2    = (const float*)d_in[12];
    const float* ab2    = (const float*)d_in[13];
    const float* fw     = (const float*)d_in[14];
    const float* fb     = (const float*)d_in[15];
    const float* gf     = (const float*)d_in[16];
    const float* bef    = (const float*)d_in[17];
    float* out = (float*)d_out;

    float* wsf = (float*)d_ws;
    ushort* wb = (ushort*)wsf;                                   // 90240 ushorts
    unsigned long long* S64   = (unsigned long long*)(wsf + WS_S64);
    unsigned long long* cs64  = (unsigned long long*)(wsf + WS_CS64);
    unsigned long long* sum64 = (unsigned long long*)(wsf + WS_SUM64);
    unsigned long long* ssq64 = (unsigned long long*)(wsf + WS_SSQ64);
    float* zero_base = wsf + WS_S64;
    float* s1  = wsf + WS_DERIV;
    float* sh1 = s1 + 128;
    float* s2  = sh1 + 128;
    float* sh2 = s2 + 128;
    ushort* img_bf = (ushort*)(wsf + WS_IMG);                    // 15,335,424 ushorts

    // K1: transpose image (bf16) + zero stats region
    k_transpose<<<BB * HH * 10 * 4, 256, 0, stream>>>(img, img_bf, zero_base);
    // K1b: bf16 weights
    k_prepw<<<(WB_TOTAL + 255) / 256, 256, 0, stream>>>(w1, w2, aw1, aw2, fw, wb);
    // K2: X^T X + colsum (u64 fixed-point atomics, deterministic)
    k_xtx<<<XTX_BLOCKS, 256, 0, stream>>>(x, S64, cs64);
    // K3: finalize BN1 (algebraic, b1 folded)
    k_finalize1<<<1, 128, 0, stream>>>(S64, cs64, w1, b1, g1, be1, s1, sh1);
    // K4: fused main (MFMA), 3125 blocks, 1 barrier, 4 blocks/CU
    k_main<<<NPTS / 64, 256, 0, stream>>>(x, coords, img_bf, P2, wb, s1, sh1,
                                          b2, ab1, ab2, fb, out, sum64, ssq64);
    // K5: finalize BN2 (fixed-order slot reduce)
    k_finalize<<<1, 128, 0, stream>>>(sum64, ssq64, gf, bef, s2, sh2);
    // K6: in-place BN2 + relu
    k_bnf<<<NPTS * OUTC / 4 / 256, 256, 0, stream>>>(out, s2, sh2);
}

// Round 4
// 749.282 us; speedup vs baseline: 1.0203x; 1.0162x over previous
//
#include <hip/hip_runtime.h>
#include <hip/hip_bf16.h>

// Problem constants (match reference)
#define NPTS 200000
#define BB   4
#define C3D  64
#define C2D  128
#define HH   96
#define WW   312
#define MID  128
#define OUTC 128

// bf16 weight sub-offsets (ushort elements)
#define WB_W1   0
#define WB_W2   8192
#define WB_AW1  24576
#define WB_AW2  57344
#define WB_FW   57472
#define WB_TOTAL 90240                     // ushorts = 45120 floats

// Fixed-point scale for deterministic integer atomics
#define FXS 1048576.0f
#define FXI (1.0 / 1048576.0)

// ws layout (float offsets). All stats are u64 fixed-point (2 floats each).
#define WS_S64    45120                    // 4096 u64  -> 8192 floats
#define WS_CS64   53312                    // 64 u64    -> 128 floats
#define WS_SUM64  53440                    // 128*16 u64-> 4096 floats
#define WS_SSQ64  57536                    // 128*16 u64-> 4096 floats
#define ZERO_N    16512                    // floats to zero: 45120..61632
#define WS_DERIV  61632                    // s1,sh1,s2,sh2 : 512
#define WS_IMG    62144                    // bf16 image, 15,335,424 ushorts

typedef __attribute__((ext_vector_type(8))) short s16x8;
typedef __attribute__((ext_vector_type(4))) float f32x4;

__device__ __forceinline__ ushort f2bf(float f) {
    unsigned u = __float_as_uint(f);
    unsigned r = (u + 0x7FFFu + ((u >> 16) & 1u)) >> 16;   // RNE
    return (ushort)r;
}
__device__ __forceinline__ float bf2f(ushort u) {
    return __uint_as_float(((unsigned)u) << 16);
}
__device__ __forceinline__ void atomic_fx(unsigned long long* p, float v) {
    atomicAdd(p, (unsigned long long)(long long)llrintf(v * FXS));
}
__device__ __forceinline__ s16x8 pack_bf8(float4 a, float4 b) {
    s16x8 v;
    v[0] = (short)f2bf(a.x); v[1] = (short)f2bf(a.y);
    v[2] = (short)f2bf(a.z); v[3] = (short)f2bf(a.w);
    v[4] = (short)f2bf(b.x); v[5] = (short)f2bf(b.y);
    v[6] = (short)f2bf(b.z); v[7] = (short)f2bf(b.w);
    return v;
}
// Same-wave LDS write->read ordering: drain lgkm, block compiler motion.
#define WAVE_LDS_FENCE() do { \
    asm volatile("s_waitcnt lgkmcnt(0)" ::: "memory"); \
    __builtin_amdgcn_sched_barrier(0); \
} while (0)

// ---------------------------------------------------------------------------
// K1: transpose image (B,C,H,W) -> (B,H,W,C) bf16, and zero the stats region
// ---------------------------------------------------------------------------
__global__ __launch_bounds__(256) void k_transpose(const float* __restrict__ img,
                                                   ushort* __restrict__ img_bf,
                                                   float* __restrict__ stats) {
    __shared__ float tile[32][33];
    int flat = blockIdx.x * 256 + threadIdx.x;
    if (flat < ZERO_N) stats[flat] = 0.f;

    int bid = blockIdx.x;
    int ct = bid & 3;  bid >>= 2;          // 4 channel tiles
    int wt = bid % 10; bid /= 10;          // 10 width tiles
    int h  = bid % HH;
    int b  = bid / HH;
    int tx = threadIdx.x & 31, ty = threadIdx.x >> 5;   // 32 x 8
    int w0 = wt * 32, c0 = ct * 32;

    #pragma unroll
    for (int i = 0; i < 4; i++) {
        int c = c0 + ty + 8 * i;
        int w = w0 + tx;
        float v = 0.f;
        if (w < WW) v = img[((b * C2D + c) * HH + h) * WW + w];
        tile[ty + 8 * i][tx] = v;
    }
    __syncthreads();
    #pragma unroll
    for (int i = 0; i < 4; i++) {
        int w = w0 + ty + 8 * i;
        int c = c0 + tx;
        if (w < WW) img_bf[((b * HH + h) * WW + w) * C2D + c] = f2bf(tile[tx][ty + 8 * i]);
    }
}

// ---------------------------------------------------------------------------
// K1b: convert weights to bf16 (row-major unchanged)
// ---------------------------------------------------------------------------
__global__ __launch_bounds__(256) void k_prepw(const float* __restrict__ w1,
                                               const float* __restrict__ w2,
                                               const float* __restrict__ aw1,
                                               const float* __restrict__ aw2,
                                               const float* __restrict__ fw,
                                               ushort* __restrict__ wb) {
    int i = blockIdx.x * 256 + threadIdx.x;
    if (i >= WB_TOTAL) return;
    float v;
    if      (i < WB_W2)  v = w1[i - WB_W1];
    else if (i < WB_AW1) v = w2[i - WB_W2];
    else if (i < WB_AW2) v = aw1[i - WB_AW1];
    else if (i < WB_FW)  v = aw2[i - WB_AW2];
    else                 v = fw[i - WB_FW];
    wb[i] = f2bf(v);
}

// ---------------------------------------------------------------------------
// K2: X^T X (64x64) + colsum, fixed-point u64 atomics (deterministic)
// ---------------------------------------------------------------------------
#define XTX_ROWS_PER_BLK 256
#define XTX_BLOCKS ((NPTS + XTX_ROWS_PER_BLK - 1) / XTX_ROWS_PER_BLK)   // 782

__global__ __launch_bounds__(256) void k_xtx(const float* __restrict__ x,
                                             unsigned long long* __restrict__ S64,
                                             unsigned long long* __restrict__ cs64) {
    __shared__ float xs[64 * 68];
    int t = threadIdx.x;
    int ti = t >> 4, tj = t & 15;
    float acc[4][4];
    #pragma unroll
    for (int a = 0; a < 4; a++)
        #pragma unroll
        for (int b = 0; b < 4; b++) acc[a][b] = 0.f;
    float csum = 0.f;

    int r0 = blockIdx.x * XTX_ROWS_PER_BLK;
    int r1 = min(r0 + XTX_ROWS_PER_BLK, NPTS);

    for (int base = r0; base < r1; base += 64) {
        int nrows = r1 - base;
        if (nrows > 64) nrows = 64;
        __syncthreads();
        const float4* xg = (const float4*)(x + (long)base * C3D);
        #pragma unroll
        for (int i = 0; i < 4; i++) {
            int f4 = t + 256 * i;
            int r = f4 >> 4, k4 = f4 & 15;
            float4 v = make_float4(0.f, 0.f, 0.f, 0.f);
            if (r < nrows) v = xg[f4];
            *(float4*)(xs + r * 68 + k4 * 4) = v;
        }
        __syncthreads();
        #pragma unroll 4
        for (int r = 0; r < 64; r++) {
            float4 av = *(const float4*)(xs + r * 68 + ti * 4);
            float4 bv = *(const float4*)(xs + r * 68 + tj * 4);
            float aa[4] = {av.x, av.y, av.z, av.w};
            float bb[4] = {bv.x, bv.y, bv.z, bv.w};
            #pragma unroll
            for (int a = 0; a < 4; a++)
                #pragma unroll
                for (int b = 0; b < 4; b++) acc[a][b] += aa[a] * bb[b];
        }
        if (t < 64) {
            #pragma unroll 8
            for (int r = 0; r < 64; r++) csum += xs[r * 68 + t];
        }
    }
    #pragma unroll
    for (int a = 0; a < 4; a++)
        #pragma unroll
        for (int b = 0; b < 4; b++)
            atomic_fx(&S64[(ti * 4 + a) * 64 + tj * 4 + b], acc[a][b]);
    if (t < 64) atomic_fx(&cs64[t], csum);
}

// ---------------------------------------------------------------------------
// K3: finalize BN1 from S64/cs64 (algebraic BN-through-affine, b1 folded)
// ---------------------------------------------------------------------------
__global__ void k_finalize1(const unsigned long long* __restrict__ S64,
                            const unsigned long long* __restrict__ cs64,
                            const float* __restrict__ w1, const float* __restrict__ b1,
                            const float* __restrict__ g, const float* __restrict__ be,
                            float* __restrict__ s, float* __restrict__ sh) {
    __shared__ __align__(16) float Ss[64 * 64];
    __shared__ float cs[64];
    int t = threadIdx.x;                   // 128 threads = 128 channels
    for (int i = t; i < 4096; i += 128)
        Ss[i] = (float)((double)(long long)S64[i] * FXI);
    if (t < 64) cs[t] = (float)((double)(long long)cs64[t] * FXI);
    __syncthreads();

    float w[64];
    const float4* wg = (const float4*)(w1 + t * 64);
    #pragma unroll
    for (int k4 = 0; k4 < 16; k4++) {
        float4 wv = wg[k4];
        w[k4 * 4 + 0] = wv.x; w[k4 * 4 + 1] = wv.y;
        w[k4 * 4 + 2] = wv.z; w[k4 * 4 + 3] = wv.w;
    }
    float wc = 0.f;
    #pragma unroll
    for (int k = 0; k < 64; k++) wc += w[k] * cs[k];
    float q = 0.f;
    for (int k = 0; k < 64; k++) {
        float tk = 0.f;
        const float4* Sr = (const float4*)(Ss + k * 64);
        #pragma unroll
        for (int l4 = 0; l4 < 16; l4++) {
            float4 sv = Sr[l4];
            tk += sv.x * w[l4 * 4 + 0];
            tk += sv.y * w[l4 * 4 + 1];
            tk += sv.z * w[l4 * 4 + 2];
            tk += sv.w * w[l4 * 4 + 3];
        }
        q += w[k] * tk;
    }
    const float invN = 1.f / (float)NPTS;
    float bc = b1[t];
    float m = wc * invN + bc;
    float Eh2 = q * invN + 2.f * bc * wc * invN + bc * bc;
    float v = Eh2 - m * m;
    float sc = g[t] * rsqrtf(v + 1e-5f);
    s[t] = sc;
    sh[t] = be[t] - (wc * invN) * sc;      // (b1 - m) * sc + be
}

// ---------------------------------------------------------------------------
// K5: finalize BN2 from 16-slot u64 fixed-point sums (fixed-order reduce)
// ---------------------------------------------------------------------------
__global__ void k_finalize(const unsigned long long* __restrict__ sum64,
                           const unsigned long long* __restrict__ ssq64,
                           const float* __restrict__ g, const float* __restrict__ b,
                           float* __restrict__ s, float* __restrict__ sh) {
    int c = threadIdx.x;   // 128
    long long si = 0, qi = 0;
    for (int i = 0; i < 16; i++) {
        si += (long long)sum64[c * 16 + i];
        qi += (long long)ssq64[c * 16 + i];
    }
    float S = (float)((double)si * FXI);
    float Q = (float)((double)qi * FXI);
    const float invN = 1.f / (float)NPTS;
    float m = S * invN;
    float v = Q * invN - m * m;
    float sc = g[c] * rsqrtf(v + 1e-5f);
    s[c] = sc;
    sh[c] = b[c] - m * sc;
}

// ---------------------------------------------------------------------------
// K4: fused main kernel (MFMA bf16), 64 rows/block, 256 threads = 4 waves.
// Wave-privatized, single cross-wave barrier.
// Register-allocator context: __launch_bounds__(256, 3) is the ONLY config
// measured to produce a >64-VGPR spill-free allocation (round -1: VGPR 84,
// hbm 162 MB). (256,4) and amdgpu_waves_per_eu(4,4) both clamped to the
// 64-reg bin and spilled ~120-170 B/thread (rounds 2-3: +140-200 MB HBM).
// x fragment loads moved after the gather so the two live ranges don't stack.
// ---------------------------------------------------------------------------
__global__ __launch_bounds__(256, 3) void k_main(
    const float* __restrict__ x, const int* __restrict__ coords,
    const ushort* __restrict__ img_bf, const float* __restrict__ P2,
    const ushort* __restrict__ wb,
    const float* __restrict__ bn1s, const float* __restrict__ bn1sh,
    const float* __restrict__ b2, const float* __restrict__ ab1,
    const float* __restrict__ ab2, const float* __restrict__ fb,
    float* __restrict__ out,
    unsigned long long* __restrict__ sum64, unsigned long long* __restrict__ ssq64)
{
    __shared__ __align__(16) char smem[33792];
    ushort* combs = (ushort*)smem;         // 64 x 264 bf16
    float*  outs  = (float*)smem;          // 64 x 132 f32 (same footprint)

    const ushort* w1b  = wb + WB_W1;
    const ushort* w2b  = wb + WB_W2;
    const ushort* aw1b = wb + WB_AW1;
    const ushort* aw2b = wb + WB_AW2;
    const ushort* fwb  = wb + WB_FW;

    int t = threadIdx.x;
    int n0 = blockIdx.x * 64;
    int lane = t & 63, wv = t >> 6;
    int l15 = lane & 15, lq = lane >> 4;
    int m0 = wv * 16;

    // ---- P1a: projection, per-lane (row = m0 + (lane>>2), 4x redundant) ----
    int grow = m0 + (lane >> 2);
    int qc = lane & 3;
    int poff_[4]; float pwgt_[4];
    {
        int4 cd = *(const int4*)(coords + (long)(n0 + grow) * 4);
        int b = cd.x;
        float p0 = (float)cd.y * 0.05f;
        float p1 = (float)cd.z * 0.05f - 40.f;
        float p2 = (float)cd.w * 0.1f - 3.f;
        const float* P = P2 + b * 12;
        float cam0 = P[0] * p0 + P[1] * p1 + P[2]  * p2 + P[3];
        float cam1 = P[4] * p0 + P[5] * p1 + P[6]  * p2 + P[7];
        float cam2 = P[8] * p0 + P[9] * p1 + P[10] * p2 + P[11];
        float d = cam2 + 1e-8f;
        float px = cam0 / d, py = cam1 / d;
        float gx = fminf(fmaxf(px / (float)WW * 2.f - 1.f, -1.f), 1.f);
        float gy = fminf(fmaxf(py / (float)HH * 2.f - 1.f, -1.f), 1.f);
        float ix = ((gx + 1.f) * (float)WW - 1.f) * 0.5f;
        float iy = ((gy + 1.f) * (float)HH - 1.f) * 0.5f;
        float x0f = floorf(ix), y0f = floorf(iy);
        float wx = ix - x0f, wy = iy - y0f;
        int x0 = (int)x0f, y0 = (int)y0f;
        #pragma unroll
        for (int j = 0; j < 4; j++) {
            int xc = x0 + (j & 1), yc = y0 + (j >> 1);
            float wgt = ((j & 1) ? wx : 1.f - wx) * ((j >> 1) ? wy : 1.f - wy);
            bool valid = (xc >= 0) && (xc < WW) && (yc >= 0) && (yc < HH);
            int xcc = min(max(xc, 0), WW - 1), ycc = min(max(yc, 0), HH - 1);
            poff_[j] = ((b * HH + ycc) * WW + xcc) * C2D;
            pwgt_[j] = valid ? wgt : 0.f;
        }
    }

    // ---- P1b: bilinear gather, ONE 8-channel group at a time (8 accs) ----
    #pragma unroll
    for (int g = 0; g < 4; g++) {
        float a8[8];
        #pragma unroll
        for (int e = 0; e < 8; e++) a8[e] = 0.f;
        #pragma unroll
        for (int j = 0; j < 4; j++) {
            s16x8 v = *(const s16x8*)(img_bf + poff_[j] + qc * 32 + g * 8);
            float wgt = pwgt_[j];
            #pragma unroll
            for (int e = 0; e < 8; e++)
                a8[e] += wgt * bf2f((ushort)v[e]);
        }
        s16x8 o;
        #pragma unroll
        for (int e = 0; e < 8; e++) o[e] = (short)f2bf(a8[e]);
        *(s16x8*)(combs + grow * 264 + 128 + qc * 32 + g * 8) = o;
    }

    // ---- P1c: GEMM1 A-operand: load from global, pack to bf16 ----
    s16x8 af0, af1;
    {
        const float* xr = x + (long)(n0 + m0 + l15) * C3D;
        float4 xa0 = *(const float4*)(xr + lq * 8);
        float4 xa1 = *(const float4*)(xr + lq * 8 + 4);
        float4 xb0 = *(const float4*)(xr + 32 + lq * 8);
        float4 xb1 = *(const float4*)(xr + 32 + lq * 8 + 4);
        af0 = pack_bf8(xa0, xa1);
        af1 = pack_bf8(xb0, xb1);
    }

    // ---- P1d: GEMM1 (K=64) + BN1 + relu -> combs[:, 0:128) (h) ----
    #pragma unroll
    for (int nt = 0; nt < 8; nt++) {
        f32x4 acc = {0.f, 0.f, 0.f, 0.f};
        s16x8 bf0 = *(const s16x8*)(w1b + (nt * 16 + l15) * 64 + lq * 8);
        s16x8 bf1 = *(const s16x8*)(w1b + (nt * 16 + l15) * 64 + 32 + lq * 8);
        acc = __builtin_amdgcn_mfma_f32_16x16x32_bf16(af0, bf0, acc, 0, 0, 0);
        acc = __builtin_amdgcn_mfma_f32_16x16x32_bf16(af1, bf1, acc, 0, 0, 0);
        int c = nt * 16 + l15;
        float sc = bn1s[c], shf = bn1sh[c];
        #pragma unroll
        for (int r = 0; r < 4; r++)
            combs[(m0 + lq * 4 + r) * 264 + c] = f2bf(fmaxf(acc[r] * sc + shf, 0.f));
    }
    WAVE_LDS_FENCE();

    // ---- P2: GEMM2 (K=128) + b2 -> vfeat, overwriting h in place ----
    {
        s16x8 af2[4];
        #pragma unroll
        for (int s = 0; s < 4; s++)
            af2[s] = *(const s16x8*)(combs + (m0 + l15) * 264 + s * 32 + lq * 8);
        WAVE_LDS_FENCE();   // reads landed in regs before same-address writes
        #pragma unroll
        for (int nt = 0; nt < 8; nt++) {
            f32x4 acc = {0.f, 0.f, 0.f, 0.f};
            #pragma unroll
            for (int s = 0; s < 4; s++) {
                s16x8 bf = *(const s16x8*)(w2b + (nt * 16 + l15) * 128 + s * 32 + lq * 8);
                acc = __builtin_amdgcn_mfma_f32_16x16x32_bf16(af2[s], bf, acc, 0, 0, 0);
            }
            int c = nt * 16 + l15;
            float bb = b2[c];
            #pragma unroll
            for (int r = 0; r < 4; r++)
                combs[(m0 + lq * 4 + r) * 264 + c] = f2bf(acc[r] + bb);
        }
    }
    WAVE_LDS_FENCE();

    // ---- P3: load comb fragments once (K=256), shared by att1 and fusion ----
    s16x8 af[8];
    #pragma unroll
    for (int s = 0; s < 8; s++)
        af[s] = *(const s16x8*)(combs + (m0 + l15) * 264 + s * 32 + lq * 8);

    // ---- P4: att1 (MFMA) + att2 (per-lane dot + shfl_xor reduce) ----
    float aatt[4];
    {
        float satt[4] = {0.f, 0.f, 0.f, 0.f};
        #pragma unroll
        for (int nt = 0; nt < 8; nt++) {
            f32x4 acc = {0.f, 0.f, 0.f, 0.f};
            #pragma unroll
            for (int s = 0; s < 8; s++) {
                s16x8 bf = *(const s16x8*)(aw1b + (nt * 16 + l15) * 256 + s * 32 + lq * 8);
                acc = __builtin_amdgcn_mfma_f32_16x16x32_bf16(af[s], bf, acc, 0, 0, 0);
            }
            int c = nt * 16 + l15;
            float bb = ab1[c];
            float w2c = bf2f(aw2b[c]);
            #pragma unroll
            for (int r = 0; r < 4; r++)
                satt[r] += fmaxf(acc[r] + bb, 0.f) * w2c;
        }
        #pragma unroll
        for (int d = 1; d < 16; d <<= 1) {
            #pragma unroll
            for (int r = 0; r < 4; r++)
                satt[r] += __shfl_xor(satt[r], d, 64);
        }
        float z0 = ab2[0];
        #pragma unroll
        for (int r = 0; r < 4; r++)
            aatt[r] = 1.f / (1.f + expf(-(satt[r] + z0)));
    }

    // ---- P5: fusion GEMM, gate folded: out = a*f1 + (1-a)*f2 + fb ----
    #pragma unroll
    for (int nt = 0; nt < 8; nt++) {
        f32x4 f1 = {0.f, 0.f, 0.f, 0.f};
        f32x4 f2 = {0.f, 0.f, 0.f, 0.f};
        #pragma unroll
        for (int s = 0; s < 4; s++) {
            s16x8 bf = *(const s16x8*)(fwb + (nt * 16 + l15) * 256 + s * 32 + lq * 8);
            f1 = __builtin_amdgcn_mfma_f32_16x16x32_bf16(af[s], bf, f1, 0, 0, 0);
        }
        #pragma unroll
        for (int s = 4; s < 8; s++) {
            s16x8 bf = *(const s16x8*)(fwb + (nt * 16 + l15) * 256 + s * 32 + lq * 8);
            f2 = __builtin_amdgcn_mfma_f32_16x16x32_bf16(af[s], bf, f2, 0, 0, 0);
        }
        int c = nt * 16 + l15;
        float bb = fb[c];
        #pragma unroll
        for (int r = 0; r < 4; r++)
            outs[(m0 + lq * 4 + r) * 132 + c] =
                aatt[r] * f1[r] + (1.f - aatt[r]) * f2[r] + bb;
    }

    __syncthreads();   // the ONLY cross-wave barrier

    // ---- P6: coalesced global store + BN2 stats (fixed-point u64) ----
    {
        float4* og = (float4*)(out + (long)n0 * OUTC);
        #pragma unroll
        for (int i = 0; i < 8; i++) {
            int f4 = t + 256 * i;              // 2048 float4 = 64 rows x 32
            int row = f4 >> 5, c4 = f4 & 31;
            float4 v = *(const float4*)(outs + row * 132 + c4 * 4);
            og[row * 32 + c4] = v;
        }
        int slot = blockIdx.x & 15;
        if (t < 128) {
            float S = 0.f;
            #pragma unroll 8
            for (int row = 0; row < 64; row++) S += outs[row * 132 + t];
            atomic_fx(&sum64[t * 16 + slot], S);
        } else {
            int c = t - 128;
            float Q = 0.f;
            #pragma unroll 8
            for (int row = 0; row < 64; row++) { float v = outs[row * 132 + c]; Q += v * v; }
            atomic_fx(&ssq64[c * 16 + slot], Q);
        }
    }
}

// ---------------------------------------------------------------------------
// K6: in-place BN2 + relu on d_out
// ---------------------------------------------------------------------------
__global__ __launch_bounds__(256) void k_bnf(float* __restrict__ out,
                                             const float* __restrict__ s,
                                             const float* __restrict__ sh) {
    long i = (long)blockIdx.x * 256 + threadIdx.x;   // over 6.4M float4
    float4* p = (float4*)out;
    float4 v = p[i];
    int c4 = (int)(i & 31);
    float4 sv  = ((const float4*)s)[c4];
    float4 shv = ((const float4*)sh)[c4];
    v.x = fmaxf(v.x * sv.x + shv.x, 0.f);
    v.y = fmaxf(v.y * sv.y + shv.y, 0.f);
    v.z = fmaxf(v.z * sv.z + shv.z, 0.f);
    v.w = fmaxf(v.w * sv.w + shv.w, 0.f);
    p[i] = v;
}

// ---------------------------------------------------------------------------
extern "C" void kernel_launch(void* const* d_in, const int* in_sizes, int n_in,
                              void* d_out, int out_size, void* d_ws, size_t ws_size,
                              hipStream_t stream) {
    const float* x      = (const float*)d_in[0];
    const int*   coords = (const int*)d_in[1];
    const float* img    = (const float*)d_in[2];
    const float* P2     = (const float*)d_in[3];
    const float* w1     = (const float*)d_in[4];
    const float* b1     = (const float*)d_in[5];
    const float* g1     = (const float*)d_in[6];
    const float* be1    = (const float*)d_in[7];
    const float* w2     = (const float*)d_in[8];
    const float* b2     = (const float*)d_in[9];
    const float* aw1    = (const float*)d_in[10];
    const float* ab1    = (const float*)d_in[11];
    const float* aw2    = (const float*)d_in[12];
    const float* ab2    = (const float*)d_in[13];
    const float* fw     = (const float*)d_in[14];
    const float* fb     = (const float*)d_in[15];
    const float* gf     = (const float*)d_in[16];
    const float* bef    = (const float*)d_in[17];
    float* out = (float*)d_out;

    float* wsf = (float*)d_ws;
    ushort* wb = (ushort*)wsf;                                   // 90240 ushorts
    unsigned long long* S64   = (unsigned long long*)(wsf + WS_S64);
    unsigned long long* cs64  = (unsigned long long*)(wsf + WS_CS64);
    unsigned long long* sum64 = (unsigned long long*)(wsf + WS_SUM64);
    unsigned long long* ssq64 = (unsigned long long*)(wsf + WS_SSQ64);
    float* zero_base = wsf + WS_S64;
    float* s1  = wsf + WS_DERIV;
    float* sh1 = s1 + 128;
    float* s2  = sh1 + 128;
    float* sh2 = s2 + 128;
    ushort* img_bf = (ushort*)(wsf + WS_IMG);                    // 15,335,424 ushorts

    // K1: transpose image (bf16) + zero stats region
    k_transpose<<<BB * HH * 10 * 4, 256, 0, stream>>>(img, img_bf, zero_base);
    // K1b: bf16 weights
    k_prepw<<<(WB_TOTAL + 255) / 256, 256, 0, stream>>>(w1, w2, aw1, aw2, fw, wb);
    // K2: X^T X + colsum (u64 fixed-point atomics, deterministic)
    k_xtx<<<XTX_BLOCKS, 256, 0, stream>>>(x, S64, cs64);
    // K3: finalize BN1 (algebraic, b1 folded)
    k_finalize1<<<1, 128, 0, stream>>>(S64, cs64, w1, b1, g1, be1, s1, sh1);
    // K4: fused main (MFMA), 3125 blocks, 1 barrier
    k_main<<<NPTS / 64, 256, 0, stream>>>(x, coords, img_bf, P2, wb, s1, sh1,
                                          b2, ab1, ab2, fb, out, sum64, ssq64);
    // K5: finalize BN2 (fixed-order slot reduce)
    k_finalize<<<1, 128, 0, stream>>>(sum64, ssq64, gf, bef, s2, sh2);
    // K6: in-place BN2 + relu
    k_bnf<<<NPTS * OUTC / 4 / 256, 256, 0, stream>>>(out, s2, sh2);
}

// Round 5
// 689.597 us; speedup vs baseline: 1.1086x; 1.0866x over previous
//
#include <hip/hip_runtime.h>
#include <hip/hip_bf16.h>

// Problem constants (match reference)
#define NPTS 200000
#define BB   4
#define C3D  64
#define C2D  128
#define HH   96
#define WW   312
#define MID  128
#define OUTC 128

// bf16 weight sub-offsets (ushort elements)
#define WB_W1   0
#define WB_W2   8192
#define WB_AW1  24576
#define WB_AW2  57344
#define WB_FW   57472
#define WB_TOTAL 90240                     // ushorts = 45120 floats

// Fixed-point scale for deterministic integer atomics
#define FXS 1048576.0f
#define FXI (1.0 / 1048576.0)

// ws layout (float offsets). All stats are u64 fixed-point (2 floats each).
#define WS_S64    45120                    // 4096 u64  -> 8192 floats
#define WS_CS64   53312                    // 64 u64    -> 128 floats
#define WS_SUM64  53440                    // 128*16 u64-> 4096 floats
#define WS_SSQ64  57536                    // 128*16 u64-> 4096 floats
#define ZERO_N    16512                    // floats to zero: 45120..61632
#define WS_DERIV  61632                    // s1,sh1,s2,sh2 : 512
#define WS_IMG    62144                    // bf16 image, 15,335,424 ushorts

typedef __attribute__((ext_vector_type(8))) short s16x8;
typedef __attribute__((ext_vector_type(4))) float f32x4;

__device__ __forceinline__ ushort f2bf(float f) {
    unsigned u = __float_as_uint(f);
    unsigned r = (u + 0x7FFFu + ((u >> 16) & 1u)) >> 16;   // RNE
    return (ushort)r;
}
__device__ __forceinline__ float bf2f(ushort u) {
    return __uint_as_float(((unsigned)u) << 16);
}
__device__ __forceinline__ void atomic_fx(unsigned long long* p, float v) {
    atomicAdd(p, (unsigned long long)(long long)llrintf(v * FXS));
}
__device__ __forceinline__ s16x8 pack_bf8(float4 a, float4 b) {
    s16x8 v;
    v[0] = (short)f2bf(a.x); v[1] = (short)f2bf(a.y);
    v[2] = (short)f2bf(a.z); v[3] = (short)f2bf(a.w);
    v[4] = (short)f2bf(b.x); v[5] = (short)f2bf(b.y);
    v[6] = (short)f2bf(b.z); v[7] = (short)f2bf(b.w);
    return v;
}
// Same-wave LDS write->read ordering: drain lgkm, block compiler motion.
#define WAVE_LDS_FENCE() do { \
    asm volatile("s_waitcnt lgkmcnt(0)" ::: "memory"); \
    __builtin_amdgcn_sched_barrier(0); \
} while (0)

// ---------------------------------------------------------------------------
// K1: transpose image (B,C,H,W) -> (B,H,W,C) bf16, and zero the stats region
// ---------------------------------------------------------------------------
__global__ __launch_bounds__(256) void k_transpose(const float* __restrict__ img,
                                                   ushort* __restrict__ img_bf,
                                                   float* __restrict__ stats) {
    __shared__ float tile[32][33];
    int flat = blockIdx.x * 256 + threadIdx.x;
    if (flat < ZERO_N) stats[flat] = 0.f;

    int bid = blockIdx.x;
    int ct = bid & 3;  bid >>= 2;          // 4 channel tiles
    int wt = bid % 10; bid /= 10;          // 10 width tiles
    int h  = bid % HH;
    int b  = bid / HH;
    int tx = threadIdx.x & 31, ty = threadIdx.x >> 5;   // 32 x 8
    int w0 = wt * 32, c0 = ct * 32;

    #pragma unroll
    for (int i = 0; i < 4; i++) {
        int c = c0 + ty + 8 * i;
        int w = w0 + tx;
        float v = 0.f;
        if (w < WW) v = img[((b * C2D + c) * HH + h) * WW + w];
        tile[ty + 8 * i][tx] = v;
    }
    __syncthreads();
    #pragma unroll
    for (int i = 0; i < 4; i++) {
        int w = w0 + ty + 8 * i;
        int c = c0 + tx;
        if (w < WW) img_bf[((b * HH + h) * WW + w) * C2D + c] = f2bf(tile[tx][ty + 8 * i]);
    }
}

// ---------------------------------------------------------------------------
// K1b: convert weights to bf16 (row-major unchanged)
// ---------------------------------------------------------------------------
__global__ __launch_bounds__(256) void k_prepw(const float* __restrict__ w1,
                                               const float* __restrict__ w2,
                                               const float* __restrict__ aw1,
                                               const float* __restrict__ aw2,
                                               const float* __restrict__ fw,
                                               ushort* __restrict__ wb) {
    int i = blockIdx.x * 256 + threadIdx.x;
    if (i >= WB_TOTAL) return;
    float v;
    if      (i < WB_W2)  v = w1[i - WB_W1];
    else if (i < WB_AW1) v = w2[i - WB_W2];
    else if (i < WB_AW2) v = aw1[i - WB_AW1];
    else if (i < WB_FW)  v = aw2[i - WB_AW2];
    else                 v = fw[i - WB_FW];
    wb[i] = f2bf(v);
}

// ---------------------------------------------------------------------------
// K2: X^T X (64x64) + colsum, fixed-point u64 atomics (deterministic)
// ---------------------------------------------------------------------------
#define XTX_ROWS_PER_BLK 256
#define XTX_BLOCKS ((NPTS + XTX_ROWS_PER_BLK - 1) / XTX_ROWS_PER_BLK)   // 782

__global__ __launch_bounds__(256) void k_xtx(const float* __restrict__ x,
                                             unsigned long long* __restrict__ S64,
                                             unsigned long long* __restrict__ cs64) {
    __shared__ float xs[64 * 68];
    int t = threadIdx.x;
    int ti = t >> 4, tj = t & 15;
    float acc[4][4];
    #pragma unroll
    for (int a = 0; a < 4; a++)
        #pragma unroll
        for (int b = 0; b < 4; b++) acc[a][b] = 0.f;
    float csum = 0.f;

    int r0 = blockIdx.x * XTX_ROWS_PER_BLK;
    int r1 = min(r0 + XTX_ROWS_PER_BLK, NPTS);

    for (int base = r0; base < r1; base += 64) {
        int nrows = r1 - base;
        if (nrows > 64) nrows = 64;
        __syncthreads();
        const float4* xg = (const float4*)(x + (long)base * C3D);
        #pragma unroll
        for (int i = 0; i < 4; i++) {
            int f4 = t + 256 * i;
            int r = f4 >> 4, k4 = f4 & 15;
            float4 v = make_float4(0.f, 0.f, 0.f, 0.f);
            if (r < nrows) v = xg[f4];
            *(float4*)(xs + r * 68 + k4 * 4) = v;
        }
        __syncthreads();
        #pragma unroll 4
        for (int r = 0; r < 64; r++) {
            float4 av = *(const float4*)(xs + r * 68 + ti * 4);
            float4 bv = *(const float4*)(xs + r * 68 + tj * 4);
            float aa[4] = {av.x, av.y, av.z, av.w};
            float bb[4] = {bv.x, bv.y, bv.z, bv.w};
            #pragma unroll
            for (int a = 0; a < 4; a++)
                #pragma unroll
                for (int b = 0; b < 4; b++) acc[a][b] += aa[a] * bb[b];
        }
        if (t < 64) {
            #pragma unroll 8
            for (int r = 0; r < 64; r++) csum += xs[r * 68 + t];
        }
    }
    #pragma unroll
    for (int a = 0; a < 4; a++)
        #pragma unroll
        for (int b = 0; b < 4; b++)
            atomic_fx(&S64[(ti * 4 + a) * 64 + tj * 4 + b], acc[a][b]);
    if (t < 64) atomic_fx(&cs64[t], csum);
}

// ---------------------------------------------------------------------------
// K3: finalize BN1 from S64/cs64 (algebraic BN-through-affine, b1 folded)
// ---------------------------------------------------------------------------
__global__ void k_finalize1(const unsigned long long* __restrict__ S64,
                            const unsigned long long* __restrict__ cs64,
                            const float* __restrict__ w1, const float* __restrict__ b1,
                            const float* __restrict__ g, const float* __restrict__ be,
                            float* __restrict__ s, float* __restrict__ sh) {
    __shared__ __align__(16) float Ss[64 * 64];
    __shared__ float cs[64];
    int t = threadIdx.x;                   // 128 threads = 128 channels
    for (int i = t; i < 4096; i += 128)
        Ss[i] = (float)((double)(long long)S64[i] * FXI);
    if (t < 64) cs[t] = (float)((double)(long long)cs64[t] * FXI);
    __syncthreads();

    float w[64];
    const float4* wg = (const float4*)(w1 + t * 64);
    #pragma unroll
    for (int k4 = 0; k4 < 16; k4++) {
        float4 wv = wg[k4];
        w[k4 * 4 + 0] = wv.x; w[k4 * 4 + 1] = wv.y;
        w[k4 * 4 + 2] = wv.z; w[k4 * 4 + 3] = wv.w;
    }
    float wc = 0.f;
    #pragma unroll
    for (int k = 0; k < 64; k++) wc += w[k] * cs[k];
    float q = 0.f;
    for (int k = 0; k < 64; k++) {
        float tk = 0.f;
        const float4* Sr = (const float4*)(Ss + k * 64);
        #pragma unroll
        for (int l4 = 0; l4 < 16; l4++) {
            float4 sv = Sr[l4];
            tk += sv.x * w[l4 * 4 + 0];
            tk += sv.y * w[l4 * 4 + 1];
            tk += sv.z * w[l4 * 4 + 2];
            tk += sv.w * w[l4 * 4 + 3];
        }
        q += w[k] * tk;
    }
    const float invN = 1.f / (float)NPTS;
    float bc = b1[t];
    float m = wc * invN + bc;
    float Eh2 = q * invN + 2.f * bc * wc * invN + bc * bc;
    float v = Eh2 - m * m;
    float sc = g[t] * rsqrtf(v + 1e-5f);
    s[t] = sc;
    sh[t] = be[t] - (wc * invN) * sc;      // (b1 - m) * sc + be
}

// ---------------------------------------------------------------------------
// K5: finalize BN2 from 16-slot u64 fixed-point sums (fixed-order reduce)
// ---------------------------------------------------------------------------
__global__ void k_finalize(const unsigned long long* __restrict__ sum64,
                           const unsigned long long* __restrict__ ssq64,
                           const float* __restrict__ g, const float* __restrict__ b,
                           float* __restrict__ s, float* __restrict__ sh) {
    int c = threadIdx.x;   // 128
    long long si = 0, qi = 0;
    for (int i = 0; i < 16; i++) {
        si += (long long)sum64[c * 16 + i];
        qi += (long long)ssq64[c * 16 + i];
    }
    float S = (float)((double)si * FXI);
    float Q = (float)((double)qi * FXI);
    const float invN = 1.f / (float)NPTS;
    float m = S * invN;
    float v = Q * invN - m * m;
    float sc = g[c] * rsqrtf(v + 1e-5f);
    s[c] = sc;
    sh[c] = b[c] - m * sc;
}

// ---------------------------------------------------------------------------
// K4: fused main kernel (MFMA bf16), 64 rows/block, 256 threads = 4 waves.
// Round-5 restructure: att1 + fusion are N-SPLIT — wave wv computes output
// cols [32wv, 32wv+32) for ALL 64 rows, loading only its slice of aw1/fw.
// This cuts per-block weight traffic 704 KB -> 320 KB (was 4x redundant:
// every wave streamed the full 176 KB weight set; 2.2 GB aggregate cache
// traffic = the measured 145K-cycle per-wave stall, rounds -1..4 all ~300us
// regardless of barrier count). GEMM1/GEMM2 stay M-split (proven numerics).
// att2: per-wave partial dot -> shfl over l15 -> a_part LDS -> fixed-order
// cross-wave sum (deterministic), overlapped with fusion MFMAs.
// Fusion accs held in regs across the barrier (outs aliases combs).
// ---------------------------------------------------------------------------
__global__ __launch_bounds__(256, 3) void k_main(
    const float* __restrict__ x, const int* __restrict__ coords,
    const ushort* __restrict__ img_bf, const float* __restrict__ P2,
    const ushort* __restrict__ wb,
    const float* __restrict__ bn1s, const float* __restrict__ bn1sh,
    const float* __restrict__ b2, const float* __restrict__ ab1,
    const float* __restrict__ ab2, const float* __restrict__ fb,
    float* __restrict__ out,
    unsigned long long* __restrict__ sum64, unsigned long long* __restrict__ ssq64)
{
    __shared__ __align__(16) char smem[35072];
    ushort* combs  = (ushort*)smem;          // 64 x 264 bf16 (33792 B)
    float*  outs   = (float*)smem;           // 64 x 132 f32 (same footprint)
    float*  a_part = (float*)(smem + 33792); // 4 x 64 f32 (1024 B)
    float*  a_s    = (float*)(smem + 34816); // 64 f32 (256 B)

    const ushort* w1b  = wb + WB_W1;
    const ushort* w2b  = wb + WB_W2;
    const ushort* aw1b = wb + WB_AW1;
    const ushort* aw2b = wb + WB_AW2;
    const ushort* fwb  = wb + WB_FW;

    int t = threadIdx.x;
    int n0 = blockIdx.x * 64;
    int lane = t & 63, wv = t >> 6;
    int l15 = lane & 15, lq = lane >> 4;
    int m0 = wv * 16;
    int cb = wv * 32;                        // N-split column base

    // ---- P1a: projection, per-lane (row = m0 + (lane>>2), 4x redundant) ----
    int grow = m0 + (lane >> 2);
    int qc = lane & 3;
    int poff_[4]; float pwgt_[4];
    {
        int4 cd = *(const int4*)(coords + (long)(n0 + grow) * 4);
        int b = cd.x;
        float p0 = (float)cd.y * 0.05f;
        float p1 = (float)cd.z * 0.05f - 40.f;
        float p2 = (float)cd.w * 0.1f - 3.f;
        const float* P = P2 + b * 12;
        float cam0 = P[0] * p0 + P[1] * p1 + P[2]  * p2 + P[3];
        float cam1 = P[4] * p0 + P[5] * p1 + P[6]  * p2 + P[7];
        float cam2 = P[8] * p0 + P[9] * p1 + P[10] * p2 + P[11];
        float d = cam2 + 1e-8f;
        float px = cam0 / d, py = cam1 / d;
        float gx = fminf(fmaxf(px / (float)WW * 2.f - 1.f, -1.f), 1.f);
        float gy = fminf(fmaxf(py / (float)HH * 2.f - 1.f, -1.f), 1.f);
        float ix = ((gx + 1.f) * (float)WW - 1.f) * 0.5f;
        float iy = ((gy + 1.f) * (float)HH - 1.f) * 0.5f;
        float x0f = floorf(ix), y0f = floorf(iy);
        float wx = ix - x0f, wy = iy - y0f;
        int x0 = (int)x0f, y0 = (int)y0f;
        #pragma unroll
        for (int j = 0; j < 4; j++) {
            int xc = x0 + (j & 1), yc = y0 + (j >> 1);
            float wgt = ((j & 1) ? wx : 1.f - wx) * ((j >> 1) ? wy : 1.f - wy);
            bool valid = (xc >= 0) && (xc < WW) && (yc >= 0) && (yc < HH);
            int xcc = min(max(xc, 0), WW - 1), ycc = min(max(yc, 0), HH - 1);
            poff_[j] = ((b * HH + ycc) * WW + xcc) * C2D;
            pwgt_[j] = valid ? wgt : 0.f;
        }
    }

    // ---- P1b: bilinear gather, ONE 8-channel group at a time (8 accs) ----
    #pragma unroll
    for (int g = 0; g < 4; g++) {
        float a8[8];
        #pragma unroll
        for (int e = 0; e < 8; e++) a8[e] = 0.f;
        #pragma unroll
        for (int j = 0; j < 4; j++) {
            s16x8 v = *(const s16x8*)(img_bf + poff_[j] + qc * 32 + g * 8);
            float wgt = pwgt_[j];
            #pragma unroll
            for (int e = 0; e < 8; e++)
                a8[e] += wgt * bf2f((ushort)v[e]);
        }
        s16x8 o;
        #pragma unroll
        for (int e = 0; e < 8; e++) o[e] = (short)f2bf(a8[e]);
        *(s16x8*)(combs + grow * 264 + 128 + qc * 32 + g * 8) = o;
    }

    // ---- P1c: GEMM1 A-operand: load from global, pack to bf16 ----
    s16x8 af0, af1;
    {
        const float* xr = x + (long)(n0 + m0 + l15) * C3D;
        float4 xa0 = *(const float4*)(xr + lq * 8);
        float4 xa1 = *(const float4*)(xr + lq * 8 + 4);
        float4 xb0 = *(const float4*)(xr + 32 + lq * 8);
        float4 xb1 = *(const float4*)(xr + 32 + lq * 8 + 4);
        af0 = pack_bf8(xa0, xa1);
        af1 = pack_bf8(xb0, xb1);
    }

    // ---- P1d: GEMM1 (K=64, M-split) + BN1 + relu -> combs[:, 0:128) ----
    #pragma unroll
    for (int nt = 0; nt < 8; nt++) {
        f32x4 acc = {0.f, 0.f, 0.f, 0.f};
        s16x8 bf0 = *(const s16x8*)(w1b + (nt * 16 + l15) * 64 + lq * 8);
        s16x8 bf1 = *(const s16x8*)(w1b + (nt * 16 + l15) * 64 + 32 + lq * 8);
        acc = __builtin_amdgcn_mfma_f32_16x16x32_bf16(af0, bf0, acc, 0, 0, 0);
        acc = __builtin_amdgcn_mfma_f32_16x16x32_bf16(af1, bf1, acc, 0, 0, 0);
        int c = nt * 16 + l15;
        float sc = bn1s[c], shf = bn1sh[c];
        #pragma unroll
        for (int r = 0; r < 4; r++)
            combs[(m0 + lq * 4 + r) * 264 + c] = f2bf(fmaxf(acc[r] * sc + shf, 0.f));
    }
    WAVE_LDS_FENCE();

    // ---- P2: GEMM2 (K=128, M-split) + b2 -> vfeat, overwriting h in place ----
    {
        s16x8 af2[4];
        #pragma unroll
        for (int s = 0; s < 4; s++)
            af2[s] = *(const s16x8*)(combs + (m0 + l15) * 264 + s * 32 + lq * 8);
        WAVE_LDS_FENCE();   // reads landed in regs before same-address writes
        #pragma unroll
        for (int nt = 0; nt < 8; nt++) {
            f32x4 acc = {0.f, 0.f, 0.f, 0.f};
            #pragma unroll
            for (int s = 0; s < 4; s++) {
                s16x8 bf = *(const s16x8*)(w2b + (nt * 16 + l15) * 128 + s * 32 + lq * 8);
                acc = __builtin_amdgcn_mfma_f32_16x16x32_bf16(af2[s], bf, acc, 0, 0, 0);
            }
            int c = nt * 16 + l15;
            float bb = b2[c];
            #pragma unroll
            for (int r = 0; r < 4; r++)
                combs[(m0 + lq * 4 + r) * 264 + c] = f2bf(acc[r] + bb);
        }
    }
    __syncthreads();   // B1: combs (vfeat+ifeat) complete for ALL rows

    // ---- P3: att1 N-split (wave's 32 cols x all 64 rows) + partial att2 ----
    #pragma unroll
    for (int mt = 0; mt < 4; mt++) {
        s16x8 afm[8];
        #pragma unroll
        for (int s = 0; s < 8; s++)
            afm[s] = *(const s16x8*)(combs + (mt * 16 + l15) * 264 + s * 32 + lq * 8);
        float sp[4] = {0.f, 0.f, 0.f, 0.f};
        #pragma unroll
        for (int nt2 = 0; nt2 < 2; nt2++) {
            int c = cb + nt2 * 16 + l15;
            f32x4 acc = {0.f, 0.f, 0.f, 0.f};
            #pragma unroll
            for (int s = 0; s < 8; s++) {
                s16x8 bf = *(const s16x8*)(aw1b + c * 256 + s * 32 + lq * 8);
                acc = __builtin_amdgcn_mfma_f32_16x16x32_bf16(afm[s], bf, acc, 0, 0, 0);
            }
            float bb = ab1[c];
            float w2c = bf2f(aw2b[c]);
            #pragma unroll
            for (int r = 0; r < 4; r++)
                sp[r] += fmaxf(acc[r] + bb, 0.f) * w2c;
        }
        #pragma unroll
        for (int d = 1; d < 16; d <<= 1) {
            #pragma unroll
            for (int r = 0; r < 4; r++)
                sp[r] += __shfl_xor(sp[r], d, 64);
        }
        if (l15 == 0) {
            f32x4 v = {sp[0], sp[1], sp[2], sp[3]};
            *(f32x4*)(a_part + wv * 64 + mt * 16 + lq * 4) = v;
        }
    }
    __syncthreads();   // B2: a_part complete

    // ---- P4: att2 cross-wave reduce (t<64), overlapped with P5 MFMAs ----
    if (t < 64) {
        float s0 = ab2[0] + a_part[t] + a_part[64 + t] + a_part[128 + t]
                 + a_part[192 + t];
        a_s[t] = 1.f / (1.f + expf(-s0));
    }

    // ---- P5: fusion N-split, accs held in regs across the barrier ----
    f32x4 fv[4][2], fi[4][2];          // [mt][nt2]: vfeat-part, ifeat-part
    #pragma unroll
    for (int mt = 0; mt < 4; mt++) {
        s16x8 afm[8];
        #pragma unroll
        for (int s = 0; s < 8; s++)
            afm[s] = *(const s16x8*)(combs + (mt * 16 + l15) * 264 + s * 32 + lq * 8);
        #pragma unroll
        for (int nt2 = 0; nt2 < 2; nt2++) {
            int c = cb + nt2 * 16 + l15;
            f32x4 f1 = {0.f, 0.f, 0.f, 0.f};
            f32x4 f2 = {0.f, 0.f, 0.f, 0.f};
            #pragma unroll
            for (int s = 0; s < 4; s++) {
                s16x8 bf = *(const s16x8*)(fwb + c * 256 + s * 32 + lq * 8);
                f1 = __builtin_amdgcn_mfma_f32_16x16x32_bf16(afm[s], bf, f1, 0, 0, 0);
            }
            #pragma unroll
            for (int s = 4; s < 8; s++) {
                s16x8 bf = *(const s16x8*)(fwb + c * 256 + s * 32 + lq * 8);
                f2 = __builtin_amdgcn_mfma_f32_16x16x32_bf16(afm[s], bf, f2, 0, 0, 0);
            }
            fv[mt][nt2] = f1;
            fi[mt][nt2] = f2;
        }
    }
    __syncthreads();   // B3: all combs reads done, a_s ready -> outs may alias

    #pragma unroll
    for (int mt = 0; mt < 4; mt++) {
        f32x4 av = *(const f32x4*)(a_s + mt * 16 + lq * 4);
        #pragma unroll
        for (int nt2 = 0; nt2 < 2; nt2++) {
            int c = cb + nt2 * 16 + l15;
            float bbv = fb[c];
            #pragma unroll
            for (int r = 0; r < 4; r++)
                outs[(mt * 16 + lq * 4 + r) * 132 + c] =
                    av[r] * fv[mt][nt2][r] + (1.f - av[r]) * fi[mt][nt2][r] + bbv;
        }
    }
    __syncthreads();   // B4: outs complete

    // ---- P6: coalesced global store + BN2 stats (fixed-point u64) ----
    {
        float4* og = (float4*)(out + (long)n0 * OUTC);
        #pragma unroll
        for (int i = 0; i < 8; i++) {
            int f4 = t + 256 * i;              // 2048 float4 = 64 rows x 32
            int row = f4 >> 5, c4 = f4 & 31;
            float4 v = *(const float4*)(outs + row * 132 + c4 * 4);
            og[row * 32 + c4] = v;
        }
        int slot = blockIdx.x & 15;
        if (t < 128) {
            float S = 0.f;
            #pragma unroll 8
            for (int row = 0; row < 64; row++) S += outs[row * 132 + t];
            atomic_fx(&sum64[t * 16 + slot], S);
        } else {
            int c = t - 128;
            float Q = 0.f;
            #pragma unroll 8
            for (int row = 0; row < 64; row++) { float v = outs[row * 132 + c]; Q += v * v; }
            atomic_fx(&ssq64[c * 16 + slot], Q);
        }
    }
}

// ---------------------------------------------------------------------------
// K6: in-place BN2 + relu on d_out
// ---------------------------------------------------------------------------
__global__ __launch_bounds__(256) void k_bnf(float* __restrict__ out,
                                             const float* __restrict__ s,
                                             const float* __restrict__ sh) {
    long i = (long)blockIdx.x * 256 + threadIdx.x;   // over 6.4M float4
    float4* p = (float4*)out;
    float4 v = p[i];
    int c4 = (int)(i & 31);
    float4 sv  = ((const float4*)s)[c4];
    float4 shv = ((const float4*)sh)[c4];
    v.x = fmaxf(v.x * sv.x + shv.x, 0.f);
    v.y = fmaxf(v.y * sv.y + shv.y, 0.f);
    v.z = fmaxf(v.z * sv.z + shv.z, 0.f);
    v.w = fmaxf(v.w * sv.w + shv.w, 0.f);
    p[i] = v;
}

// ---------------------------------------------------------------------------
extern "C" void kernel_launch(void* const* d_in, const int* in_sizes, int n_in,
                              void* d_out, int out_size, void* d_ws, size_t ws_size,
                              hipStream_t stream) {
    const float* x      = (const float*)d_in[0];
    const int*   coords = (const int*)d_in[1];
    const float* img    = (const float*)d_in[2];
    const float* P2     = (const float*)d_in[3];
    const float* w1     = (const float*)d_in[4];
    const float* b1     = (const float*)d_in[5];
    const float* g1     = (const float*)d_in[6];
    const float* be1    = (const float*)d_in[7];
    const float* w2     = (const float*)d_in[8];
    const float* b2     = (const float*)d_in[9];
    const float* aw1    = (const float*)d_in[10];
    const float* ab1    = (const float*)d_in[11];
    const float* aw2    = (const float*)d_in[12];
    const float* ab2    = (const float*)d_in[13];
    const float* fw     = (const float*)d_in[14];
    const float* fb     = (const float*)d_in[15];
    const float* gf     = (const float*)d_in[16];
    const float* bef    = (const float*)d_in[17];
    float* out = (float*)d_out;

    float* wsf = (float*)d_ws;
    ushort* wb = (ushort*)wsf;                                   // 90240 ushorts
    unsigned long long* S64   = (unsigned long long*)(wsf + WS_S64);
    unsigned long long* cs64  = (unsigned long long*)(wsf + WS_CS64);
    unsigned long long* sum64 = (unsigned long long*)(wsf + WS_SUM64);
    unsigned long long* ssq64 = (unsigned long long*)(wsf + WS_SSQ64);
    float* zero_base = wsf + WS_S64;
    float* s1  = wsf + WS_DERIV;
    float* sh1 = s1 + 128;
    float* s2  = sh1 + 128;
    float* sh2 = s2 + 128;
    ushort* img_bf = (ushort*)(wsf + WS_IMG);                    // 15,335,424 ushorts

    // K1: transpose image (bf16) + zero stats region
    k_transpose<<<BB * HH * 10 * 4, 256, 0, stream>>>(img, img_bf, zero_base);
    // K1b: bf16 weights
    k_prepw<<<(WB_TOTAL + 255) / 256, 256, 0, stream>>>(w1, w2, aw1, aw2, fw, wb);
    // K2: X^T X + colsum (u64 fixed-point atomics, deterministic)
    k_xtx<<<XTX_BLOCKS, 256, 0, stream>>>(x, S64, cs64);
    // K3: finalize BN1 (algebraic, b1 folded)
    k_finalize1<<<1, 128, 0, stream>>>(S64, cs64, w1, b1, g1, be1, s1, sh1);
    // K4: fused main (MFMA), 3125 blocks, N-split att1/fusion
    k_main<<<NPTS / 64, 256, 0, stream>>>(x, coords, img_bf, P2, wb, s1, sh1,
                                          b2, ab1, ab2, fb, out, sum64, ssq64);
    // K5: finalize BN2 (fixed-order slot reduce)
    k_finalize<<<1, 128, 0, stream>>>(sum64, ssq64, gf, bef, s2, sh2);
    // K6: in-place BN2 + relu
    k_bnf<<<NPTS * OUTC / 4 / 256, 256, 0, stream>>>(out, s2, sh2);
}

// Round 6
// 603.606 us; speedup vs baseline: 1.2666x; 1.1425x over previous
//
#include <hip/hip_runtime.h>
#include <hip/hip_bf16.h>

// Problem constants (match reference)
#define NPTS 200000
#define BB   4
#define C3D  64
#define C2D  128
#define HH   96
#define WW   312
#define MID  128
#define OUTC 128

// bf16 weight sub-offsets (ushort elements)
#define WB_W1   0
#define WB_W2   8192
#define WB_AW1  24576
#define WB_AW2  57344
#define WB_FW   57472
#define WB_TOTAL 90240                     // ushorts = 45120 floats

// Fixed-point scale for deterministic integer atomics
#define FXS 1048576.0f
#define FXI (1.0 / 1048576.0)

// ws layout (float offsets). All stats are u64 fixed-point (2 floats each).
#define WS_S64    45120                    // 4096 u64  -> 8192 floats
#define WS_CS64   53312                    // 64 u64    -> 128 floats
#define WS_SUM64  53440                    // 128*16 u64-> 4096 floats
#define WS_SSQ64  57536                    // 128*16 u64-> 4096 floats
#define ZERO_N    16512                    // floats to zero: 45120..61632
#define WS_DERIV  61632                    // s1,sh1,s2,sh2 : 512
#define WS_IMG    62144                    // bf16 image, 15,335,424 ushorts

typedef __attribute__((ext_vector_type(8))) short s16x8;
typedef __attribute__((ext_vector_type(4))) float f32x4;

__device__ __forceinline__ ushort f2bf(float f) {
    unsigned u = __float_as_uint(f);
    unsigned r = (u + 0x7FFFu + ((u >> 16) & 1u)) >> 16;   // RNE
    return (ushort)r;
}
__device__ __forceinline__ float bf2f(ushort u) {
    return __uint_as_float(((unsigned)u) << 16);
}
__device__ __forceinline__ void atomic_fx(unsigned long long* p, float v) {
    atomicAdd(p, (unsigned long long)(long long)llrintf(v * FXS));
}
__device__ __forceinline__ s16x8 pack_bf8(float4 a, float4 b) {
    s16x8 v;
    v[0] = (short)f2bf(a.x); v[1] = (short)f2bf(a.y);
    v[2] = (short)f2bf(a.z); v[3] = (short)f2bf(a.w);
    v[4] = (short)f2bf(b.x); v[5] = (short)f2bf(b.y);
    v[6] = (short)f2bf(b.z); v[7] = (short)f2bf(b.w);
    return v;
}

// ---------------------------------------------------------------------------
// K1: transpose image (B,C,H,W) -> (B,H,W,C) bf16, and zero the stats region
// ---------------------------------------------------------------------------
__global__ __launch_bounds__(256) void k_transpose(const float* __restrict__ img,
                                                   ushort* __restrict__ img_bf,
                                                   float* __restrict__ stats) {
    __shared__ float tile[32][33];
    int flat = blockIdx.x * 256 + threadIdx.x;
    if (flat < ZERO_N) stats[flat] = 0.f;

    int bid = blockIdx.x;
    int ct = bid & 3;  bid >>= 2;          // 4 channel tiles
    int wt = bid % 10; bid /= 10;          // 10 width tiles
    int h  = bid % HH;
    int b  = bid / HH;
    int tx = threadIdx.x & 31, ty = threadIdx.x >> 5;   // 32 x 8
    int w0 = wt * 32, c0 = ct * 32;

    #pragma unroll
    for (int i = 0; i < 4; i++) {
        int c = c0 + ty + 8 * i;
        int w = w0 + tx;
        float v = 0.f;
        if (w < WW) v = img[((b * C2D + c) * HH + h) * WW + w];
        tile[ty + 8 * i][tx] = v;
    }
    __syncthreads();
    #pragma unroll
    for (int i = 0; i < 4; i++) {
        int w = w0 + ty + 8 * i;
        int c = c0 + tx;
        if (w < WW) img_bf[((b * HH + h) * WW + w) * C2D + c] = f2bf(tile[tx][ty + 8 * i]);
    }
}

// ---------------------------------------------------------------------------
// K1b: convert weights to bf16 (row-major unchanged)
// ---------------------------------------------------------------------------
__global__ __launch_bounds__(256) void k_prepw(const float* __restrict__ w1,
                                               const float* __restrict__ w2,
                                               const float* __restrict__ aw1,
                                               const float* __restrict__ aw2,
                                               const float* __restrict__ fw,
                                               ushort* __restrict__ wb) {
    int i = blockIdx.x * 256 + threadIdx.x;
    if (i >= WB_TOTAL) return;
    float v;
    if      (i < WB_W2)  v = w1[i - WB_W1];
    else if (i < WB_AW1) v = w2[i - WB_W2];
    else if (i < WB_AW2) v = aw1[i - WB_AW1];
    else if (i < WB_FW)  v = aw2[i - WB_AW2];
    else                 v = fw[i - WB_FW];
    wb[i] = f2bf(v);
}

// ---------------------------------------------------------------------------
// K2: X^T X (64x64) + colsum, fixed-point u64 atomics (deterministic)
// ---------------------------------------------------------------------------
#define XTX_ROWS_PER_BLK 256
#define XTX_BLOCKS ((NPTS + XTX_ROWS_PER_BLK - 1) / XTX_ROWS_PER_BLK)   // 782

__global__ __launch_bounds__(256) void k_xtx(const float* __restrict__ x,
                                             unsigned long long* __restrict__ S64,
                                             unsigned long long* __restrict__ cs64) {
    __shared__ float xs[64 * 68];
    int t = threadIdx.x;
    int ti = t >> 4, tj = t & 15;
    float acc[4][4];
    #pragma unroll
    for (int a = 0; a < 4; a++)
        #pragma unroll
        for (int b = 0; b < 4; b++) acc[a][b] = 0.f;
    float csum = 0.f;

    int r0 = blockIdx.x * XTX_ROWS_PER_BLK;
    int r1 = min(r0 + XTX_ROWS_PER_BLK, NPTS);

    for (int base = r0; base < r1; base += 64) {
        int nrows = r1 - base;
        if (nrows > 64) nrows = 64;
        __syncthreads();
        const float4* xg = (const float4*)(x + (long)base * C3D);
        #pragma unroll
        for (int i = 0; i < 4; i++) {
            int f4 = t + 256 * i;
            int r = f4 >> 4, k4 = f4 & 15;
            float4 v = make_float4(0.f, 0.f, 0.f, 0.f);
            if (r < nrows) v = xg[f4];
            *(float4*)(xs + r * 68 + k4 * 4) = v;
        }
        __syncthreads();
        #pragma unroll 4
        for (int r = 0; r < 64; r++) {
            float4 av = *(const float4*)(xs + r * 68 + ti * 4);
            float4 bv = *(const float4*)(xs + r * 68 + tj * 4);
            float aa[4] = {av.x, av.y, av.z, av.w};
            float bb[4] = {bv.x, bv.y, bv.z, bv.w};
            #pragma unroll
            for (int a = 0; a < 4; a++)
                #pragma unroll
                for (int b = 0; b < 4; b++) acc[a][b] += aa[a] * bb[b];
        }
        if (t < 64) {
            #pragma unroll 8
            for (int r = 0; r < 64; r++) csum += xs[r * 68 + t];
        }
    }
    #pragma unroll
    for (int a = 0; a < 4; a++)
        #pragma unroll
        for (int b = 0; b < 4; b++)
            atomic_fx(&S64[(ti * 4 + a) * 64 + tj * 4 + b], acc[a][b]);
    if (t < 64) atomic_fx(&cs64[t], csum);
}

// ---------------------------------------------------------------------------
// K3: finalize BN1 from S64/cs64 (algebraic BN-through-affine, b1 folded)
// ---------------------------------------------------------------------------
__global__ void k_finalize1(const unsigned long long* __restrict__ S64,
                            const unsigned long long* __restrict__ cs64,
                            const float* __restrict__ w1, const float* __restrict__ b1,
                            const float* __restrict__ g, const float* __restrict__ be,
                            float* __restrict__ s, float* __restrict__ sh) {
    __shared__ __align__(16) float Ss[64 * 64];
    __shared__ float cs[64];
    int t = threadIdx.x;                   // 128 threads = 128 channels
    for (int i = t; i < 4096; i += 128)
        Ss[i] = (float)((double)(long long)S64[i] * FXI);
    if (t < 64) cs[t] = (float)((double)(long long)cs64[t] * FXI);
    __syncthreads();

    float w[64];
    const float4* wg = (const float4*)(w1 + t * 64);
    #pragma unroll
    for (int k4 = 0; k4 < 16; k4++) {
        float4 wv = wg[k4];
        w[k4 * 4 + 0] = wv.x; w[k4 * 4 + 1] = wv.y;
        w[k4 * 4 + 2] = wv.z; w[k4 * 4 + 3] = wv.w;
    }
    float wc = 0.f;
    #pragma unroll
    for (int k = 0; k < 64; k++) wc += w[k] * cs[k];
    float q = 0.f;
    for (int k = 0; k < 64; k++) {
        float tk = 0.f;
        const float4* Sr = (const float4*)(Ss + k * 64);
        #pragma unroll
        for (int l4 = 0; l4 < 16; l4++) {
            float4 sv = Sr[l4];
            tk += sv.x * w[l4 * 4 + 0];
            tk += sv.y * w[l4 * 4 + 1];
            tk += sv.z * w[l4 * 4 + 2];
            tk += sv.w * w[l4 * 4 + 3];
        }
        q += w[k] * tk;
    }
    const float invN = 1.f / (float)NPTS;
    float bc = b1[t];
    float m = wc * invN + bc;
    float Eh2 = q * invN + 2.f * bc * wc * invN + bc * bc;
    float v = Eh2 - m * m;
    float sc = g[t] * rsqrtf(v + 1e-5f);
    s[t] = sc;
    sh[t] = be[t] - (wc * invN) * sc;      // (b1 - m) * sc + be
}

// ---------------------------------------------------------------------------
// K5: finalize BN2 from 16-slot u64 fixed-point sums (fixed-order reduce)
// ---------------------------------------------------------------------------
__global__ void k_finalize(const unsigned long long* __restrict__ sum64,
                           const unsigned long long* __restrict__ ssq64,
                           const float* __restrict__ g, const float* __restrict__ b,
                           float* __restrict__ s, float* __restrict__ sh) {
    int c = threadIdx.x;   // 128
    long long si = 0, qi = 0;
    for (int i = 0; i < 16; i++) {
        si += (long long)sum64[c * 16 + i];
        qi += (long long)ssq64[c * 16 + i];
    }
    float S = (float)((double)si * FXI);
    float Q = (float)((double)qi * FXI);
    const float invN = 1.f / (float)NPTS;
    float m = S * invN;
    float v = Q * invN - m * m;
    float sc = g[c] * rsqrtf(v + 1e-5f);
    s[c] = sc;
    sh[c] = b[c] - m * sc;
}

// ---------------------------------------------------------------------------
// K4: fused main kernel (MFMA bf16), 64 rows/block, 256 threads = 4 waves.
// Round-6: everything after GEMM1 is N-SPLIT (wave wv owns output cols
// [32wv,32wv+32)); weight slices hoisted to registers OUTSIDE the mt loop
// (each slice fetched once per wave: w1 16K + w2 8K + aw1 16K + fw 16K =
// 56 KB/wave vs round-5's 176 KB). Gate applied in-LDS before fusion
// (round -1 proven numerics) so fusion needs ONE acc set (32 VGPR).
// All sched_barrier pins removed; cross-phase ordering via __syncthreads
// (proven free in round 4). vacc/facc held in regs across the read-write
// barrier because outs/vfeat alias the combs region other waves still read.
// ---------------------------------------------------------------------------
__global__ __launch_bounds__(256, 3) void k_main(
    const float* __restrict__ x, const int* __restrict__ coords,
    const ushort* __restrict__ img_bf, const float* __restrict__ P2,
    const ushort* __restrict__ wb,
    const float* __restrict__ bn1s, const float* __restrict__ bn1sh,
    const float* __restrict__ b2, const float* __restrict__ ab1,
    const float* __restrict__ ab2, const float* __restrict__ fb,
    float* __restrict__ out,
    unsigned long long* __restrict__ sum64, unsigned long long* __restrict__ ssq64)
{
    __shared__ __align__(16) char smem[34816];
    ushort* combs  = (ushort*)smem;          // 64 x 264 bf16 (33792 B)
    float*  outs   = (float*)smem;           // 64 x 132 f32 (same footprint)
    float*  a_part = (float*)(smem + 33792); // 4 x 64 f32 (1024 B)

    const ushort* w1b  = wb + WB_W1;
    const ushort* w2b  = wb + WB_W2;
    const ushort* aw1b = wb + WB_AW1;
    const ushort* aw2b = wb + WB_AW2;
    const ushort* fwb  = wb + WB_FW;

    int t = threadIdx.x;
    int n0 = blockIdx.x * 64;
    int lane = t & 63, wv = t >> 6;
    int l15 = lane & 15, lq = lane >> 4;
    int m0 = wv * 16;
    int cb = wv * 32;                        // N-split column base

    // ---- P1a: projection, per-lane (row = m0 + (lane>>2), 4x redundant) ----
    int grow = m0 + (lane >> 2);
    int qc = lane & 3;
    int poff_[4]; float pwgt_[4];
    {
        int4 cd = *(const int4*)(coords + (long)(n0 + grow) * 4);
        int b = cd.x;
        float p0 = (float)cd.y * 0.05f;
        float p1 = (float)cd.z * 0.05f - 40.f;
        float p2 = (float)cd.w * 0.1f - 3.f;
        const float* P = P2 + b * 12;
        float cam0 = P[0] * p0 + P[1] * p1 + P[2]  * p2 + P[3];
        float cam1 = P[4] * p0 + P[5] * p1 + P[6]  * p2 + P[7];
        float cam2 = P[8] * p0 + P[9] * p1 + P[10] * p2 + P[11];
        float d = cam2 + 1e-8f;
        float px = cam0 / d, py = cam1 / d;
        float gx = fminf(fmaxf(px / (float)WW * 2.f - 1.f, -1.f), 1.f);
        float gy = fminf(fmaxf(py / (float)HH * 2.f - 1.f, -1.f), 1.f);
        float ix = ((gx + 1.f) * (float)WW - 1.f) * 0.5f;
        float iy = ((gy + 1.f) * (float)HH - 1.f) * 0.5f;
        float x0f = floorf(ix), y0f = floorf(iy);
        float wx = ix - x0f, wy = iy - y0f;
        int x0 = (int)x0f, y0 = (int)y0f;
        #pragma unroll
        for (int j = 0; j < 4; j++) {
            int xc = x0 + (j & 1), yc = y0 + (j >> 1);
            float wgt = ((j & 1) ? wx : 1.f - wx) * ((j >> 1) ? wy : 1.f - wy);
            bool valid = (xc >= 0) && (xc < WW) && (yc >= 0) && (yc < HH);
            int xcc = min(max(xc, 0), WW - 1), ycc = min(max(yc, 0), HH - 1);
            poff_[j] = ((b * HH + ycc) * WW + xcc) * C2D;
            pwgt_[j] = valid ? wgt : 0.f;
        }
    }

    // ---- P1b: bilinear gather, ONE 8-channel group at a time (8 accs) ----
    #pragma unroll
    for (int g = 0; g < 4; g++) {
        float a8[8];
        #pragma unroll
        for (int e = 0; e < 8; e++) a8[e] = 0.f;
        #pragma unroll
        for (int j = 0; j < 4; j++) {
            s16x8 v = *(const s16x8*)(img_bf + poff_[j] + qc * 32 + g * 8);
            float wgt = pwgt_[j];
            #pragma unroll
            for (int e = 0; e < 8; e++)
                a8[e] += wgt * bf2f((ushort)v[e]);
        }
        s16x8 o;
        #pragma unroll
        for (int e = 0; e < 8; e++) o[e] = (short)f2bf(a8[e]);
        *(s16x8*)(combs + grow * 264 + 128 + qc * 32 + g * 8) = o;
    }

    // ---- P1c: GEMM1 A-operand: load from global, pack to bf16 ----
    s16x8 af0, af1;
    {
        const float* xr = x + (long)(n0 + m0 + l15) * C3D;
        float4 xa0 = *(const float4*)(xr + lq * 8);
        float4 xa1 = *(const float4*)(xr + lq * 8 + 4);
        float4 xb0 = *(const float4*)(xr + 32 + lq * 8);
        float4 xb1 = *(const float4*)(xr + 32 + lq * 8 + 4);
        af0 = pack_bf8(xa0, xa1);
        af1 = pack_bf8(xb0, xb1);
    }

    // ---- P1d: GEMM1 (K=64, M-split) + BN1 + relu -> combs[:, 0:128) ----
    #pragma unroll
    for (int nt = 0; nt < 8; nt++) {
        f32x4 acc = {0.f, 0.f, 0.f, 0.f};
        s16x8 bf0 = *(const s16x8*)(w1b + (nt * 16 + l15) * 64 + lq * 8);
        s16x8 bf1 = *(const s16x8*)(w1b + (nt * 16 + l15) * 64 + 32 + lq * 8);
        acc = __builtin_amdgcn_mfma_f32_16x16x32_bf16(af0, bf0, acc, 0, 0, 0);
        acc = __builtin_amdgcn_mfma_f32_16x16x32_bf16(af1, bf1, acc, 0, 0, 0);
        int c = nt * 16 + l15;
        float sc = bn1s[c], shf = bn1sh[c];
        #pragma unroll
        for (int r = 0; r < 4; r++)
            combs[(m0 + lq * 4 + r) * 264 + c] = f2bf(fmaxf(acc[r] * sc + shf, 0.f));
    }
    __syncthreads();   // B1: h + ifeat complete for ALL rows

    // ---- P2: GEMM2 N-split (wave's 32 cols x all 64 rows), w2 slice 8 KB ----
    f32x4 vacc[4][2];
    #pragma unroll
    for (int nt2 = 0; nt2 < 2; nt2++) {
        int c = cb + nt2 * 16 + l15;
        s16x8 wf[4];
        #pragma unroll
        for (int s = 0; s < 4; s++)
            wf[s] = *(const s16x8*)(w2b + c * 128 + s * 32 + lq * 8);
        #pragma unroll
        for (int mt = 0; mt < 4; mt++) {
            s16x8 ah[4];
            #pragma unroll
            for (int s = 0; s < 4; s++)
                ah[s] = *(const s16x8*)(combs + (mt * 16 + l15) * 264 + s * 32 + lq * 8);
            f32x4 acc = {0.f, 0.f, 0.f, 0.f};
            #pragma unroll
            for (int s = 0; s < 4; s++)
                acc = __builtin_amdgcn_mfma_f32_16x16x32_bf16(ah[s], wf[s], acc, 0, 0, 0);
            vacc[mt][nt2] = acc;
        }
    }
    __syncthreads();   // B2: all h reads done -> vfeat may overwrite h

    #pragma unroll
    for (int nt2 = 0; nt2 < 2; nt2++) {
        int c = cb + nt2 * 16 + l15;
        float bb = b2[c];
        #pragma unroll
        for (int mt = 0; mt < 4; mt++)
            #pragma unroll
            for (int r = 0; r < 4; r++)
                combs[(mt * 16 + lq * 4 + r) * 264 + c] = f2bf(vacc[mt][nt2][r] + bb);
    }
    __syncthreads();   // B3: vfeat complete; combs = [vfeat | ifeat]

    // ---- P3: att1 N-split, aw1 slice hoisted (16 KB once per wave) ----
    float sp[4][4];
    #pragma unroll
    for (int mt = 0; mt < 4; mt++)
        #pragma unroll
        for (int r = 0; r < 4; r++) sp[mt][r] = 0.f;
    #pragma unroll
    for (int nt2 = 0; nt2 < 2; nt2++) {
        int c = cb + nt2 * 16 + l15;
        s16x8 wf[8];
        #pragma unroll
        for (int s = 0; s < 8; s++)
            wf[s] = *(const s16x8*)(aw1b + c * 256 + s * 32 + lq * 8);
        float bb = ab1[c];
        float w2c = bf2f(aw2b[c]);
        #pragma unroll
        for (int mt = 0; mt < 4; mt++) {
            s16x8 afm[8];
            #pragma unroll
            for (int s = 0; s < 8; s++)
                afm[s] = *(const s16x8*)(combs + (mt * 16 + l15) * 264 + s * 32 + lq * 8);
            f32x4 acc = {0.f, 0.f, 0.f, 0.f};
            #pragma unroll
            for (int s = 0; s < 8; s++)
                acc = __builtin_amdgcn_mfma_f32_16x16x32_bf16(afm[s], wf[s], acc, 0, 0, 0);
            #pragma unroll
            for (int r = 0; r < 4; r++)
                sp[mt][r] += fmaxf(acc[r] + bb, 0.f) * w2c;
        }
    }
    #pragma unroll
    for (int d = 1; d < 16; d <<= 1) {
        #pragma unroll
        for (int mt = 0; mt < 4; mt++)
            #pragma unroll
            for (int r = 0; r < 4; r++)
                sp[mt][r] += __shfl_xor(sp[mt][r], d, 64);
    }
    if (l15 == 0) {
        #pragma unroll
        for (int mt = 0; mt < 4; mt++) {
            f32x4 v = {sp[mt][0], sp[mt][1], sp[mt][2], sp[mt][3]};
            *(f32x4*)(a_part + wv * 64 + mt * 16 + lq * 4) = v;
        }
    }
    __syncthreads();   // B4: a_part complete AND all att combs reads done

    // ---- P4: gate combs in place (wave-private rows), a computed per-lane ----
    {
        int row = m0 + l15;                // wave wv gates its own 16 rows
        float s0 = ab2[0] + a_part[row] + a_part[64 + row] + a_part[128 + row]
                 + a_part[192 + row];
        float a = 1.f / (1.f + expf(-s0));
        #pragma unroll
        for (int j = 0; j < 8; j++) {
            int ch = lq * 8 + j;           // 32 chunks of 8 cols per row
            float f = (ch < 16) ? a : 1.f - a;
            ushort* p = combs + row * 264 + ch * 8;
            s16x8 v = *(s16x8*)p;
            s16x8 o;
            #pragma unroll
            for (int e = 0; e < 8; e++) o[e] = (short)f2bf(bf2f((ushort)v[e]) * f);
            *(s16x8*)p = o;
        }
    }
    __syncthreads();   // B5: gated combs complete

    // ---- P5: fusion N-split (K=256), fw slice hoisted, ONE acc set ----
    f32x4 facc[4][2];
    #pragma unroll
    for (int nt2 = 0; nt2 < 2; nt2++) {
        int c = cb + nt2 * 16 + l15;
        s16x8 wf[8];
        #pragma unroll
        for (int s = 0; s < 8; s++)
            wf[s] = *(const s16x8*)(fwb + c * 256 + s * 32 + lq * 8);
        #pragma unroll
        for (int mt = 0; mt < 4; mt++) {
            s16x8 afm[8];
            #pragma unroll
            for (int s = 0; s < 8; s++)
                afm[s] = *(const s16x8*)(combs + (mt * 16 + l15) * 264 + s * 32 + lq * 8);
            f32x4 acc = {0.f, 0.f, 0.f, 0.f};
            #pragma unroll
            for (int s = 0; s < 8; s++)
                acc = __builtin_amdgcn_mfma_f32_16x16x32_bf16(afm[s], wf[s], acc, 0, 0, 0);
            facc[mt][nt2] = acc;
        }
    }
    __syncthreads();   // B6: all fusion reads done -> outs may alias combs

    #pragma unroll
    for (int nt2 = 0; nt2 < 2; nt2++) {
        int c = cb + nt2 * 16 + l15;
        float bb = fb[c];
        #pragma unroll
        for (int mt = 0; mt < 4; mt++)
            #pragma unroll
            for (int r = 0; r < 4; r++)
                outs[(mt * 16 + lq * 4 + r) * 132 + c] = facc[mt][nt2][r] + bb;
    }
    __syncthreads();   // B7: outs complete

    // ---- P6: coalesced global store + BN2 stats (fixed-point u64) ----
    {
        float4* og = (float4*)(out + (long)n0 * OUTC);
        #pragma unroll
        for (int i = 0; i < 8; i++) {
            int f4 = t + 256 * i;              // 2048 float4 = 64 rows x 32
            int row = f4 >> 5, c4 = f4 & 31;
            float4 v = *(const float4*)(outs + row * 132 + c4 * 4);
            og[row * 32 + c4] = v;
        }
        int slot = blockIdx.x & 15;
        if (t < 128) {
            float S = 0.f;
            #pragma unroll 8
            for (int row = 0; row < 64; row++) S += outs[row * 132 + t];
            atomic_fx(&sum64[t * 16 + slot], S);
        } else {
            int c = t - 128;
            float Q = 0.f;
            #pragma unroll 8
            for (int row = 0; row < 64; row++) { float v = outs[row * 132 + c]; Q += v * v; }
            atomic_fx(&ssq64[c * 16 + slot], Q);
        }
    }
}

// ---------------------------------------------------------------------------
// K6: in-place BN2 + relu on d_out
// ---------------------------------------------------------------------------
__global__ __launch_bounds__(256) void k_bnf(float* __restrict__ out,
                                             const float* __restrict__ s,
                                             const float* __restrict__ sh) {
    long i = (long)blockIdx.x * 256 + threadIdx.x;   // over 6.4M float4
    float4* p = (float4*)out;
    float4 v = p[i];
    int c4 = (int)(i & 31);
    float4 sv  = ((const float4*)s)[c4];
    float4 shv = ((const float4*)sh)[c4];
    v.x = fmaxf(v.x * sv.x + shv.x, 0.f);
    v.y = fmaxf(v.y * sv.y + shv.y, 0.f);
    v.z = fmaxf(v.z * sv.z + shv.z, 0.f);
    v.w = fmaxf(v.w * sv.w + shv.w, 0.f);
    p[i] = v;
}

// ---------------------------------------------------------------------------
extern "C" void kernel_launch(void* const* d_in, const int* in_sizes, int n_in,
                              void* d_out, int out_size, void* d_ws, size_t ws_size,
                              hipStream_t stream) {
    const float* x      = (const float*)d_in[0];
    const int*   coords = (const int*)d_in[1];
    const float* img    = (const float*)d_in[2];
    const float* P2     = (const float*)d_in[3];
    const float* w1     = (const float*)d_in[4];
    const float* b1     = (const float*)d_in[5];
    const float* g1     = (const float*)d_in[6];
    const float* be1    = (const float*)d_in[7];
    const float* w2     = (const float*)d_in[8];
    const float* b2     = (const float*)d_in[9];
    const float* aw1    = (const float*)d_in[10];
    const float* ab1    = (const float*)d_in[11];
    const float* aw2    = (const float*)d_in[12];
    const float* ab2    = (const float*)d_in[13];
    const float* fw     = (const float*)d_in[14];
    const float* fb     = (const float*)d_in[15];
    const float* gf     = (const float*)d_in[16];
    const float* bef    = (const float*)d_in[17];
    float* out = (float*)d_out;

    float* wsf = (float*)d_ws;
    ushort* wb = (ushort*)wsf;                                   // 90240 ushorts
    unsigned long long* S64   = (unsigned long long*)(wsf + WS_S64);
    unsigned long long* cs64  = (unsigned long long*)(wsf + WS_CS64);
    unsigned long long* sum64 = (unsigned long long*)(wsf + WS_SUM64);
    unsigned long long* ssq64 = (unsigned long long*)(wsf + WS_SSQ64);
    float* zero_base = wsf + WS_S64;
    float* s1  = wsf + WS_DERIV;
    float* sh1 = s1 + 128;
    float* s2  = sh1 + 128;
    float* sh2 = s2 + 128;
    ushort* img_bf = (ushort*)(wsf + WS_IMG);                    // 15,335,424 ushorts

    // K1: transpose image (bf16) + zero stats region
    k_transpose<<<BB * HH * 10 * 4, 256, 0, stream>>>(img, img_bf, zero_base);
    // K1b: bf16 weights
    k_prepw<<<(WB_TOTAL + 255) / 256, 256, 0, stream>>>(w1, w2, aw1, aw2, fw, wb);
    // K2: X^T X + colsum (u64 fixed-point atomics, deterministic)
    k_xtx<<<XTX_BLOCKS, 256, 0, stream>>>(x, S64, cs64);
    // K3: finalize BN1 (algebraic, b1 folded)
    k_finalize1<<<1, 128, 0, stream>>>(S64, cs64, w1, b1, g1, be1, s1, sh1);
    // K4: fused main (MFMA), 3125 blocks, all-N-split + reg-resident weights
    k_main<<<NPTS / 64, 256, 0, stream>>>(x, coords, img_bf, P2, wb, s1, sh1,
                                          b2, ab1, ab2, fb, out, sum64, ssq64);
    // K5: finalize BN2 (fixed-order slot reduce)
    k_finalize<<<1, 128, 0, stream>>>(sum64, ssq64, gf, bef, s2, sh2);
    // K6: in-place BN2 + relu
    k_bnf<<<NPTS * OUTC / 4 / 256, 256, 0, stream>>>(out, s2, sh2);
}

// Round 7
// 584.050 us; speedup vs baseline: 1.3090x; 1.0335x over previous
//
#include <hip/hip_runtime.h>
#include <hip/hip_bf16.h>

// Problem constants (match reference)
#define NPTS 200000
#define BB   4
#define C3D  64
#define C2D  128
#define HH   96
#define WW   312
#define MID  128
#define OUTC 128

// bf16 weight sub-offsets (ushort elements)
#define WB_W1   0
#define WB_W2   8192
#define WB_AW1  24576
#define WB_AW2  57344
#define WB_FW   57472
#define WB_TOTAL 90240                     // ushorts = 45120 floats

// Fixed-point scale for deterministic integer atomics
#define FXS 1048576.0f
#define FXI (1.0 / 1048576.0)

// ws layout (float offsets). All stats are u64 fixed-point (2 floats each).
#define WS_S64    45120                    // 4096 u64  -> 8192 floats
#define WS_CS64   53312                    // 64 u64    -> 128 floats
#define WS_SUM64  53440                    // 128*16 u64-> 4096 floats
#define WS_SSQ64  57536                    // 128*16 u64-> 4096 floats
#define ZERO_N    16512                    // floats to zero: 45120..61632
#define WS_DERIV  61632                    // s1,sh1 : 256 (s2/sh2 slots unused now)
#define WS_IMG    62144                    // bf16 image, 15,335,424 ushorts

typedef __attribute__((ext_vector_type(8))) short s16x8;
typedef __attribute__((ext_vector_type(4))) float f32x4;

__device__ __forceinline__ ushort f2bf(float f) {
    unsigned u = __float_as_uint(f);
    unsigned r = (u + 0x7FFFu + ((u >> 16) & 1u)) >> 16;   // RNE
    return (ushort)r;
}
__device__ __forceinline__ float bf2f(ushort u) {
    return __uint_as_float(((unsigned)u) << 16);
}
__device__ __forceinline__ void atomic_fx(unsigned long long* p, float v) {
    atomicAdd(p, (unsigned long long)(long long)llrintf(v * FXS));
}
__device__ __forceinline__ s16x8 pack_bf8(float4 a, float4 b) {
    s16x8 v;
    v[0] = (short)f2bf(a.x); v[1] = (short)f2bf(a.y);
    v[2] = (short)f2bf(a.z); v[3] = (short)f2bf(a.w);
    v[4] = (short)f2bf(b.x); v[5] = (short)f2bf(b.y);
    v[6] = (short)f2bf(b.z); v[7] = (short)f2bf(b.w);
    return v;
}

// ---------------------------------------------------------------------------
// K1: transpose image (B,C,H,W) -> (B,H,W,C) bf16; zero stats region;
//     convert weights to bf16 (folded-in former k_prepw — flat side job).
// ---------------------------------------------------------------------------
__global__ __launch_bounds__(256) void k_transpose(const float* __restrict__ img,
                                                   ushort* __restrict__ img_bf,
                                                   float* __restrict__ stats,
                                                   const float* __restrict__ w1,
                                                   const float* __restrict__ w2,
                                                   const float* __restrict__ aw1,
                                                   const float* __restrict__ aw2,
                                                   const float* __restrict__ fw,
                                                   ushort* __restrict__ wb) {
    __shared__ float tile[32][33];
    int flat = blockIdx.x * 256 + threadIdx.x;
    if (flat < ZERO_N) stats[flat] = 0.f;
    if (flat < WB_TOTAL) {
        float v;
        if      (flat < WB_W2)  v = w1[flat - WB_W1];
        else if (flat < WB_AW1) v = w2[flat - WB_W2];
        else if (flat < WB_AW2) v = aw1[flat - WB_AW1];
        else if (flat < WB_FW)  v = aw2[flat - WB_AW2];
        else                    v = fw[flat - WB_FW];
        wb[flat] = f2bf(v);
    }

    int bid = blockIdx.x;
    int ct = bid & 3;  bid >>= 2;          // 4 channel tiles
    int wt = bid % 10; bid /= 10;          // 10 width tiles
    int h  = bid % HH;
    int b  = bid / HH;
    int tx = threadIdx.x & 31, ty = threadIdx.x >> 5;   // 32 x 8
    int w0 = wt * 32, c0 = ct * 32;

    #pragma unroll
    for (int i = 0; i < 4; i++) {
        int c = c0 + ty + 8 * i;
        int w = w0 + tx;
        float v = 0.f;
        if (w < WW) v = img[((b * C2D + c) * HH + h) * WW + w];
        tile[ty + 8 * i][tx] = v;
    }
    __syncthreads();
    #pragma unroll
    for (int i = 0; i < 4; i++) {
        int w = w0 + ty + 8 * i;
        int c = c0 + tx;
        if (w < WW) img_bf[((b * HH + h) * WW + w) * C2D + c] = f2bf(tile[tx][ty + 8 * i]);
    }
}

// ---------------------------------------------------------------------------
// K2: X^T X (64x64) + colsum. Round-7: atomic-throughput was the bound
// (3.2M u64 atomics at ~8/cyc chip-wide = the whole 166 us).
//   - 250 blocks x 800 rows (was 782 x 256): atomics /3.1
//   - S symmetric: only row<=col cells atomically added (k_finalize1 mirrors)
//   - register-prefetch double-buffer hides global latency in the 13-tile loop
// Atomics: 3.2M -> ~520K. Values bit-identical (same f32 partials, u64 adds).
// ---------------------------------------------------------------------------
#define XTX_ROWS_PER_BLK 800
#define XTX_BLOCKS ((NPTS + XTX_ROWS_PER_BLK - 1) / XTX_ROWS_PER_BLK)   // 250

__global__ __launch_bounds__(256) void k_xtx(const float* __restrict__ x,
                                             unsigned long long* __restrict__ S64,
                                             unsigned long long* __restrict__ cs64) {
    __shared__ float xs[64 * 68];
    int t = threadIdx.x;
    int ti = t >> 4, tj = t & 15;
    float acc[4][4];
    #pragma unroll
    for (int a = 0; a < 4; a++)
        #pragma unroll
        for (int b = 0; b < 4; b++) acc[a][b] = 0.f;
    float csum = 0.f;

    int r0 = blockIdx.x * XTX_ROWS_PER_BLK;
    int r1 = min(r0 + XTX_ROWS_PER_BLK, NPTS);

    // prefetch tile 0 into registers
    float4 pf[4];
    {
        int nrows = min(r1 - r0, 64);
        const float4* xg = (const float4*)(x + (long)r0 * C3D);
        #pragma unroll
        for (int i = 0; i < 4; i++) {
            int f4 = t + 256 * i;
            pf[i] = ((f4 >> 4) < nrows) ? xg[f4] : make_float4(0.f, 0.f, 0.f, 0.f);
        }
    }

    for (int base = r0; base < r1; base += 64) {
        __syncthreads();                   // prev compute done -> LDS writable
        #pragma unroll
        for (int i = 0; i < 4; i++) {
            int f4 = t + 256 * i;
            int r = f4 >> 4, k4 = f4 & 15;
            *(float4*)(xs + r * 68 + k4 * 4) = pf[i];
        }
        // prefetch next tile (lands during compute below)
        int nb = base + 64;
        if (nb < r1) {
            int nrows = min(r1 - nb, 64);
            const float4* xg = (const float4*)(x + (long)nb * C3D);
            #pragma unroll
            for (int i = 0; i < 4; i++) {
                int f4 = t + 256 * i;
                pf[i] = ((f4 >> 4) < nrows) ? xg[f4] : make_float4(0.f, 0.f, 0.f, 0.f);
            }
        }
        __syncthreads();                   // LDS tile ready
        #pragma unroll 4
        for (int r = 0; r < 64; r++) {
            float4 av = *(const float4*)(xs + r * 68 + ti * 4);
            float4 bv = *(const float4*)(xs + r * 68 + tj * 4);
            float aa[4] = {av.x, av.y, av.z, av.w};
            float bb[4] = {bv.x, bv.y, bv.z, bv.w};
            #pragma unroll
            for (int a = 0; a < 4; a++)
                #pragma unroll
                for (int b = 0; b < 4; b++) acc[a][b] += aa[a] * bb[b];
        }
        if (t < 64) {
            #pragma unroll 8
            for (int r = 0; r < 64; r++) csum += xs[r * 68 + t];
        }
    }
    // triangle-predicated atomics (S symmetric; mirror applied in k_finalize1)
    #pragma unroll
    for (int a = 0; a < 4; a++)
        #pragma unroll
        for (int b = 0; b < 4; b++) {
            int row = ti * 4 + a, col = tj * 4 + b;
            if (row <= col) atomic_fx(&S64[row * 64 + col], acc[a][b]);
        }
    if (t < 64) atomic_fx(&cs64[t], csum);
}

// ---------------------------------------------------------------------------
// K3: finalize BN1 from S64/cs64 (algebraic BN-through-affine, b1 folded)
// S64 holds only the upper triangle -> mirror on load.
// ---------------------------------------------------------------------------
__global__ void k_finalize1(const unsigned long long* __restrict__ S64,
                            const unsigned long long* __restrict__ cs64,
                            const float* __restrict__ w1, const float* __restrict__ b1,
                            const float* __restrict__ g, const float* __restrict__ be,
                            float* __restrict__ s, float* __restrict__ sh) {
    __shared__ __align__(16) float Ss[64 * 64];
    __shared__ float cs[64];
    int t = threadIdx.x;                   // 128 threads = 128 channels
    for (int i = t; i < 4096; i += 128) {
        int r = i >> 6, c = i & 63;
        long long v = (long long)((r <= c) ? S64[i] : S64[c * 64 + r]);
        Ss[i] = (float)((double)v * FXI);
    }
    if (t < 64) cs[t] = (float)((double)(long long)cs64[t] * FXI);
    __syncthreads();

    float w[64];
    const float4* wg = (const float4*)(w1 + t * 64);
    #pragma unroll
    for (int k4 = 0; k4 < 16; k4++) {
        float4 wv = wg[k4];
        w[k4 * 4 + 0] = wv.x; w[k4 * 4 + 1] = wv.y;
        w[k4 * 4 + 2] = wv.z; w[k4 * 4 + 3] = wv.w;
    }
    float wc = 0.f;
    #pragma unroll
    for (int k = 0; k < 64; k++) wc += w[k] * cs[k];
    float q = 0.f;
    for (int k = 0; k < 64; k++) {
        float tk = 0.f;
        const float4* Sr = (const float4*)(Ss + k * 64);
        #pragma unroll
        for (int l4 = 0; l4 < 16; l4++) {
            float4 sv = Sr[l4];
            tk += sv.x * w[l4 * 4 + 0];
            tk += sv.y * w[l4 * 4 + 1];
            tk += sv.z * w[l4 * 4 + 2];
            tk += sv.w * w[l4 * 4 + 3];
        }
        q += w[k] * tk;
    }
    const float invN = 1.f / (float)NPTS;
    float bc = b1[t];
    float m = wc * invN + bc;
    float Eh2 = q * invN + 2.f * bc * wc * invN + bc * bc;
    float v = Eh2 - m * m;
    float sc = g[t] * rsqrtf(v + 1e-5f);
    s[t] = sc;
    sh[t] = be[t] - (wc * invN) * sc;      // (b1 - m) * sc + be
}

// ---------------------------------------------------------------------------
// K4: fused main kernel (round-6 structure, unchanged: all-N-split,
// reg-resident weight slices, 56 KB weights/wave, 7 barriers).
// ---------------------------------------------------------------------------
__global__ __launch_bounds__(256, 3) void k_main(
    const float* __restrict__ x, const int* __restrict__ coords,
    const ushort* __restrict__ img_bf, const float* __restrict__ P2,
    const ushort* __restrict__ wb,
    const float* __restrict__ bn1s, const float* __restrict__ bn1sh,
    const float* __restrict__ b2, const float* __restrict__ ab1,
    const float* __restrict__ ab2, const float* __restrict__ fb,
    float* __restrict__ out,
    unsigned long long* __restrict__ sum64, unsigned long long* __restrict__ ssq64)
{
    __shared__ __align__(16) char smem[34816];
    ushort* combs  = (ushort*)smem;          // 64 x 264 bf16 (33792 B)
    float*  outs   = (float*)smem;           // 64 x 132 f32 (same footprint)
    float*  a_part = (float*)(smem + 33792); // 4 x 64 f32 (1024 B)

    const ushort* w1b  = wb + WB_W1;
    const ushort* w2b  = wb + WB_W2;
    const ushort* aw1b = wb + WB_AW1;
    const ushort* aw2b = wb + WB_AW2;
    const ushort* fwb  = wb + WB_FW;

    int t = threadIdx.x;
    int n0 = blockIdx.x * 64;
    int lane = t & 63, wv = t >> 6;
    int l15 = lane & 15, lq = lane >> 4;
    int m0 = wv * 16;
    int cb = wv * 32;                        // N-split column base

    // ---- P1a: projection, per-lane (row = m0 + (lane>>2), 4x redundant) ----
    int grow = m0 + (lane >> 2);
    int qc = lane & 3;
    int poff_[4]; float pwgt_[4];
    {
        int4 cd = *(const int4*)(coords + (long)(n0 + grow) * 4);
        int b = cd.x;
        float p0 = (float)cd.y * 0.05f;
        float p1 = (float)cd.z * 0.05f - 40.f;
        float p2 = (float)cd.w * 0.1f - 3.f;
        const float* P = P2 + b * 12;
        float cam0 = P[0] * p0 + P[1] * p1 + P[2]  * p2 + P[3];
        float cam1 = P[4] * p0 + P[5] * p1 + P[6]  * p2 + P[7];
        float cam2 = P[8] * p0 + P[9] * p1 + P[10] * p2 + P[11];
        float d = cam2 + 1e-8f;
        float px = cam0 / d, py = cam1 / d;
        float gx = fminf(fmaxf(px / (float)WW * 2.f - 1.f, -1.f), 1.f);
        float gy = fminf(fmaxf(py / (float)HH * 2.f - 1.f, -1.f), 1.f);
        float ix = ((gx + 1.f) * (float)WW - 1.f) * 0.5f;
        float iy = ((gy + 1.f) * (float)HH - 1.f) * 0.5f;
        float x0f = floorf(ix), y0f = floorf(iy);
        float wx = ix - x0f, wy = iy - y0f;
        int x0 = (int)x0f, y0 = (int)y0f;
        #pragma unroll
        for (int j = 0; j < 4; j++) {
            int xc = x0 + (j & 1), yc = y0 + (j >> 1);
            float wgt = ((j & 1) ? wx : 1.f - wx) * ((j >> 1) ? wy : 1.f - wy);
            bool valid = (xc >= 0) && (xc < WW) && (yc >= 0) && (yc < HH);
            int xcc = min(max(xc, 0), WW - 1), ycc = min(max(yc, 0), HH - 1);
            poff_[j] = ((b * HH + ycc) * WW + xcc) * C2D;
            pwgt_[j] = valid ? wgt : 0.f;
        }
    }

    // ---- P1b: bilinear gather, ONE 8-channel group at a time (8 accs) ----
    #pragma unroll
    for (int g = 0; g < 4; g++) {
        float a8[8];
        #pragma unroll
        for (int e = 0; e < 8; e++) a8[e] = 0.f;
        #pragma unroll
        for (int j = 0; j < 4; j++) {
            s16x8 v = *(const s16x8*)(img_bf + poff_[j] + qc * 32 + g * 8);
            float wgt = pwgt_[j];
            #pragma unroll
            for (int e = 0; e < 8; e++)
                a8[e] += wgt * bf2f((ushort)v[e]);
        }
        s16x8 o;
        #pragma unroll
        for (int e = 0; e < 8; e++) o[e] = (short)f2bf(a8[e]);
        *(s16x8*)(combs + grow * 264 + 128 + qc * 32 + g * 8) = o;
    }

    // ---- P1c: GEMM1 A-operand: load from global, pack to bf16 ----
    s16x8 af0, af1;
    {
        const float* xr = x + (long)(n0 + m0 + l15) * C3D;
        float4 xa0 = *(const float4*)(xr + lq * 8);
        float4 xa1 = *(const float4*)(xr + lq * 8 + 4);
        float4 xb0 = *(const float4*)(xr + 32 + lq * 8);
        float4 xb1 = *(const float4*)(xr + 32 + lq * 8 + 4);
        af0 = pack_bf8(xa0, xa1);
        af1 = pack_bf8(xb0, xb1);
    }

    // ---- P1d: GEMM1 (K=64, M-split) + BN1 + relu -> combs[:, 0:128) ----
    #pragma unroll
    for (int nt = 0; nt < 8; nt++) {
        f32x4 acc = {0.f, 0.f, 0.f, 0.f};
        s16x8 bf0 = *(const s16x8*)(w1b + (nt * 16 + l15) * 64 + lq * 8);
        s16x8 bf1 = *(const s16x8*)(w1b + (nt * 16 + l15) * 64 + 32 + lq * 8);
        acc = __builtin_amdgcn_mfma_f32_16x16x32_bf16(af0, bf0, acc, 0, 0, 0);
        acc = __builtin_amdgcn_mfma_f32_16x16x32_bf16(af1, bf1, acc, 0, 0, 0);
        int c = nt * 16 + l15;
        float sc = bn1s[c], shf = bn1sh[c];
        #pragma unroll
        for (int r = 0; r < 4; r++)
            combs[(m0 + lq * 4 + r) * 264 + c] = f2bf(fmaxf(acc[r] * sc + shf, 0.f));
    }
    __syncthreads();   // B1: h + ifeat complete for ALL rows

    // ---- P2: GEMM2 N-split (wave's 32 cols x all 64 rows), w2 slice 8 KB ----
    f32x4 vacc[4][2];
    #pragma unroll
    for (int nt2 = 0; nt2 < 2; nt2++) {
        int c = cb + nt2 * 16 + l15;
        s16x8 wf[4];
        #pragma unroll
        for (int s = 0; s < 4; s++)
            wf[s] = *(const s16x8*)(w2b + c * 128 + s * 32 + lq * 8);
        #pragma unroll
        for (int mt = 0; mt < 4; mt++) {
            s16x8 ah[4];
            #pragma unroll
            for (int s = 0; s < 4; s++)
                ah[s] = *(const s16x8*)(combs + (mt * 16 + l15) * 264 + s * 32 + lq * 8);
            f32x4 acc = {0.f, 0.f, 0.f, 0.f};
            #pragma unroll
            for (int s = 0; s < 4; s++)
                acc = __builtin_amdgcn_mfma_f32_16x16x32_bf16(ah[s], wf[s], acc, 0, 0, 0);
            vacc[mt][nt2] = acc;
        }
    }
    __syncthreads();   // B2: all h reads done -> vfeat may overwrite h

    #pragma unroll
    for (int nt2 = 0; nt2 < 2; nt2++) {
        int c = cb + nt2 * 16 + l15;
        float bb = b2[c];
        #pragma unroll
        for (int mt = 0; mt < 4; mt++)
            #pragma unroll
            for (int r = 0; r < 4; r++)
                combs[(mt * 16 + lq * 4 + r) * 264 + c] = f2bf(vacc[mt][nt2][r] + bb);
    }
    __syncthreads();   // B3: vfeat complete; combs = [vfeat | ifeat]

    // ---- P3: att1 N-split, aw1 slice hoisted (16 KB once per wave) ----
    float sp[4][4];
    #pragma unroll
    for (int mt = 0; mt < 4; mt++)
        #pragma unroll
        for (int r = 0; r < 4; r++) sp[mt][r] = 0.f;
    #pragma unroll
    for (int nt2 = 0; nt2 < 2; nt2++) {
        int c = cb + nt2 * 16 + l15;
        s16x8 wf[8];
        #pragma unroll
        for (int s = 0; s < 8; s++)
            wf[s] = *(const s16x8*)(aw1b + c * 256 + s * 32 + lq * 8);
        float bb = ab1[c];
        float w2c = bf2f(aw2b[c]);
        #pragma unroll
        for (int mt = 0; mt < 4; mt++) {
            s16x8 afm[8];
            #pragma unroll
            for (int s = 0; s < 8; s++)
                afm[s] = *(const s16x8*)(combs + (mt * 16 + l15) * 264 + s * 32 + lq * 8);
            f32x4 acc = {0.f, 0.f, 0.f, 0.f};
            #pragma unroll
            for (int s = 0; s < 8; s++)
                acc = __builtin_amdgcn_mfma_f32_16x16x32_bf16(afm[s], wf[s], acc, 0, 0, 0);
            #pragma unroll
            for (int r = 0; r < 4; r++)
                sp[mt][r] += fmaxf(acc[r] + bb, 0.f) * w2c;
        }
    }
    #pragma unroll
    for (int d = 1; d < 16; d <<= 1) {
        #pragma unroll
        for (int mt = 0; mt < 4; mt++)
            #pragma unroll
            for (int r = 0; r < 4; r++)
                sp[mt][r] += __shfl_xor(sp[mt][r], d, 64);
    }
    if (l15 == 0) {
        #pragma unroll
        for (int mt = 0; mt < 4; mt++) {
            f32x4 v = {sp[mt][0], sp[mt][1], sp[mt][2], sp[mt][3]};
            *(f32x4*)(a_part + wv * 64 + mt * 16 + lq * 4) = v;
        }
    }
    __syncthreads();   // B4: a_part complete AND all att combs reads done

    // ---- P4: gate combs in place (wave-private rows), a computed per-lane ----
    {
        int row = m0 + l15;                // wave wv gates its own 16 rows
        float s0 = ab2[0] + a_part[row] + a_part[64 + row] + a_part[128 + row]
                 + a_part[192 + row];
        float a = 1.f / (1.f + expf(-s0));
        #pragma unroll
        for (int j = 0; j < 8; j++) {
            int ch = lq * 8 + j;           // 32 chunks of 8 cols per row
            float f = (ch < 16) ? a : 1.f - a;
            ushort* p = combs + row * 264 + ch * 8;
            s16x8 v = *(s16x8*)p;
            s16x8 o;
            #pragma unroll
            for (int e = 0; e < 8; e++) o[e] = (short)f2bf(bf2f((ushort)v[e]) * f);
            *(s16x8*)p = o;
        }
    }
    __syncthreads();   // B5: gated combs complete

    // ---- P5: fusion N-split (K=256), fw slice hoisted, ONE acc set ----
    f32x4 facc[4][2];
    #pragma unroll
    for (int nt2 = 0; nt2 < 2; nt2++) {
        int c = cb + nt2 * 16 + l15;
        s16x8 wf[8];
        #pragma unroll
        for (int s = 0; s < 8; s++)
            wf[s] = *(const s16x8*)(fwb + c * 256 + s * 32 + lq * 8);
        #pragma unroll
        for (int mt = 0; mt < 4; mt++) {
            s16x8 afm[8];
            #pragma unroll
            for (int s = 0; s < 8; s++)
                afm[s] = *(const s16x8*)(combs + (mt * 16 + l15) * 264 + s * 32 + lq * 8);
            f32x4 acc = {0.f, 0.f, 0.f, 0.f};
            #pragma unroll
            for (int s = 0; s < 8; s++)
                acc = __builtin_amdgcn_mfma_f32_16x16x32_bf16(afm[s], wf[s], acc, 0, 0, 0);
            facc[mt][nt2] = acc;
        }
    }
    __syncthreads();   // B6: all fusion reads done -> outs may alias combs

    #pragma unroll
    for (int nt2 = 0; nt2 < 2; nt2++) {
        int c = cb + nt2 * 16 + l15;
        float bb = fb[c];
        #pragma unroll
        for (int mt = 0; mt < 4; mt++)
            #pragma unroll
            for (int r = 0; r < 4; r++)
                outs[(mt * 16 + lq * 4 + r) * 132 + c] = facc[mt][nt2][r] + bb;
    }
    __syncthreads();   // B7: outs complete

    // ---- P6: coalesced global store + BN2 stats (fixed-point u64) ----
    {
        float4* og = (float4*)(out + (long)n0 * OUTC);
        #pragma unroll
        for (int i = 0; i < 8; i++) {
            int f4 = t + 256 * i;              // 2048 float4 = 64 rows x 32
            int row = f4 >> 5, c4 = f4 & 31;
            float4 v = *(const float4*)(outs + row * 132 + c4 * 4);
            og[row * 32 + c4] = v;
        }
        int slot = blockIdx.x & 15;
        if (t < 128) {
            float S = 0.f;
            #pragma unroll 8
            for (int row = 0; row < 64; row++) S += outs[row * 132 + t];
            atomic_fx(&sum64[t * 16 + slot], S);
        } else {
            int c = t - 128;
            float Q = 0.f;
            #pragma unroll 8
            for (int row = 0; row < 64; row++) { float v = outs[row * 132 + c]; Q += v * v; }
            atomic_fx(&ssq64[c * 16 + slot], Q);
        }
    }
}

// ---------------------------------------------------------------------------
// K6: BN2 finalize (folded-in former k_finalize, computed redundantly
// per block from the 16-slot u64 sums — deterministic fixed-order) + relu.
// ---------------------------------------------------------------------------
__global__ __launch_bounds__(256) void k_bnf(float* __restrict__ out,
                                             const unsigned long long* __restrict__ sum64,
                                             const unsigned long long* __restrict__ ssq64,
                                             const float* __restrict__ g,
                                             const float* __restrict__ b) {
    __shared__ float s_s[128], s_sh[128];
    int t = threadIdx.x;
    if (t < 128) {
        long long si = 0, qi = 0;
        #pragma unroll
        for (int i = 0; i < 16; i++) {
            si += (long long)sum64[t * 16 + i];
            qi += (long long)ssq64[t * 16 + i];
        }
        float S = (float)((double)si * FXI);
        float Q = (float)((double)qi * FXI);
        const float invN = 1.f / (float)NPTS;
        float m = S * invN;
        float v = Q * invN - m * m;
        float sc = g[t] * rsqrtf(v + 1e-5f);
        s_s[t] = sc;
        s_sh[t] = b[t] - m * sc;
    }
    __syncthreads();

    long i = (long)blockIdx.x * 256 + t;   // over 6.4M float4
    float4* p = (float4*)out;
    float4 v = p[i];
    int c4 = (int)(i & 31);
    float4 sv  = *(const float4*)(s_s + c4 * 4);
    float4 shv = *(const float4*)(s_sh + c4 * 4);
    v.x = fmaxf(v.x * sv.x + shv.x, 0.f);
    v.y = fmaxf(v.y * sv.y + shv.y, 0.f);
    v.z = fmaxf(v.z * sv.z + shv.z, 0.f);
    v.w = fmaxf(v.w * sv.w + shv.w, 0.f);
    p[i] = v;
}

// ---------------------------------------------------------------------------
extern "C" void kernel_launch(void* const* d_in, const int* in_sizes, int n_in,
                              void* d_out, int out_size, void* d_ws, size_t ws_size,
                              hipStream_t stream) {
    const float* x      = (const float*)d_in[0];
    const int*   coords = (const int*)d_in[1];
    const float* img    = (const float*)d_in[2];
    const float* P2     = (const float*)d_in[3];
    const float* w1     = (const float*)d_in[4];
    const float* b1     = (const float*)d_in[5];
    const float* g1     = (const float*)d_in[6];
    const float* be1    = (const float*)d_in[7];
    const float* w2     = (const float*)d_in[8];
    const float* b2     = (const float*)d_in[9];
    const float* aw1    = (const float*)d_in[10];
    const float* ab1    = (const float*)d_in[11];
    const float* aw2    = (const float*)d_in[12];
    const float* ab2    = (const float*)d_in[13];
    const float* fw     = (const float*)d_in[14];
    const float* fb     = (const float*)d_in[15];
    const float* gf     = (const float*)d_in[16];
    const float* bef    = (const float*)d_in[17];
    float* out = (float*)d_out;

    float* wsf = (float*)d_ws;
    ushort* wb = (ushort*)wsf;                                   // 90240 ushorts
    unsigned long long* S64   = (unsigned long long*)(wsf + WS_S64);
    unsigned long long* cs64  = (unsigned long long*)(wsf + WS_CS64);
    unsigned long long* sum64 = (unsigned long long*)(wsf + WS_SUM64);
    unsigned long long* ssq64 = (unsigned long long*)(wsf + WS_SSQ64);
    float* zero_base = wsf + WS_S64;
    float* s1  = wsf + WS_DERIV;
    float* sh1 = s1 + 128;
    ushort* img_bf = (ushort*)(wsf + WS_IMG);                    // 15,335,424 ushorts

    // K1: transpose image (bf16) + zero stats + bf16 weights (merged k_prepw)
    k_transpose<<<BB * HH * 10 * 4, 256, 0, stream>>>(img, img_bf, zero_base,
                                                      w1, w2, aw1, aw2, fw, wb);
    // K2: X^T X + colsum (250 blocks, triangle atomics, reg double-buffer)
    k_xtx<<<XTX_BLOCKS, 256, 0, stream>>>(x, S64, cs64);
    // K3: finalize BN1 (algebraic, b1 folded; mirrors triangle)
    k_finalize1<<<1, 128, 0, stream>>>(S64, cs64, w1, b1, g1, be1, s1, sh1);
    // K4: fused main (MFMA), 3125 blocks, all-N-split + reg-resident weights
    k_main<<<NPTS / 64, 256, 0, stream>>>(x, coords, img_bf, P2, wb, s1, sh1,
                                          b2, ab1, ab2, fb, out, sum64, ssq64);
    // K6: BN2 finalize (per-block, deterministic) + relu (merged k_finalize)
    k_bnf<<<NPTS * OUTC / 4 / 256, 256, 0, stream>>>(out, sum64, ssq64, gf, bef);
}

// Round 8
// 469.511 us; speedup vs baseline: 1.6283x; 1.2440x over previous
//
#include <hip/hip_runtime.h>
#include <hip/hip_bf16.h>

// Problem constants (match reference)
#define NPTS 200000
#define BB   4
#define C3D  64
#define C2D  128
#define HH   96
#define WW   312
#define MID  128
#define OUTC 128

// bf16 weight sub-offsets (ushort elements)
#define WB_W1   0
#define WB_W2   8192
#define WB_AW1  24576
#define WB_AW2  57344
#define WB_FW   57472
#define WB_TOTAL 90240                     // ushorts = 45120 floats

// Fixed-point scale for deterministic integer atomics
#define FXS 1048576.0f
#define FXI (1.0 / 1048576.0)

// ws layout (float offsets). All stats are u64 fixed-point (2 floats each).
// Former S64 region now holds the h0 sum/ssq slot arrays (BN1 stats).
#define WS_H0S    45120                    // 2048 u64 (128 ch x 16 slots)
#define WS_H0Q    49216                    // 2048 u64
#define WS_SUM64  53440                    // 128*16 u64-> 4096 floats (BN2)
#define WS_SSQ64  57536                    // 128*16 u64-> 4096 floats (BN2)
#define ZERO_N    16512                    // floats to zero: 45120..61632
#define WS_DERIV  61632                    // s1,sh1 : 256
#define WS_IMG    62144                    // bf16 image, 15,335,424 ushorts

typedef __attribute__((ext_vector_type(8))) short s16x8;
typedef __attribute__((ext_vector_type(4))) float f32x4;

__device__ __forceinline__ ushort f2bf(float f) {
    unsigned u = __float_as_uint(f);
    unsigned r = (u + 0x7FFFu + ((u >> 16) & 1u)) >> 16;   // RNE
    return (ushort)r;
}
__device__ __forceinline__ float bf2f(ushort u) {
    return __uint_as_float(((unsigned)u) << 16);
}
__device__ __forceinline__ void atomic_fx(unsigned long long* p, float v) {
    atomicAdd(p, (unsigned long long)(long long)llrintf(v * FXS));
}
__device__ __forceinline__ s16x8 pack_bf8(float4 a, float4 b) {
    s16x8 v;
    v[0] = (short)f2bf(a.x); v[1] = (short)f2bf(a.y);
    v[2] = (short)f2bf(a.z); v[3] = (short)f2bf(a.w);
    v[4] = (short)f2bf(b.x); v[5] = (short)f2bf(b.y);
    v[6] = (short)f2bf(b.z); v[7] = (short)f2bf(b.w);
    return v;
}

// ---------------------------------------------------------------------------
// K1: transpose image (B,C,H,W) -> (B,H,W,C) bf16; zero stats region;
//     convert weights to bf16 (merged k_prepw).
// ---------------------------------------------------------------------------
__global__ __launch_bounds__(256) void k_transpose(const float* __restrict__ img,
                                                   ushort* __restrict__ img_bf,
                                                   float* __restrict__ stats,
                                                   const float* __restrict__ w1,
                                                   const float* __restrict__ w2,
                                                   const float* __restrict__ aw1,
                                                   const float* __restrict__ aw2,
                                                   const float* __restrict__ fw,
                                                   ushort* __restrict__ wb) {
    __shared__ float tile[32][33];
    int flat = blockIdx.x * 256 + threadIdx.x;
    if (flat < ZERO_N) stats[flat] = 0.f;
    if (flat < WB_TOTAL) {
        float v;
        if      (flat < WB_W2)  v = w1[flat - WB_W1];
        else if (flat < WB_AW1) v = w2[flat - WB_W2];
        else if (flat < WB_AW2) v = aw1[flat - WB_AW1];
        else if (flat < WB_FW)  v = aw2[flat - WB_AW2];
        else                    v = fw[flat - WB_FW];
        wb[flat] = f2bf(v);
    }

    int bid = blockIdx.x;
    int ct = bid & 3;  bid >>= 2;          // 4 channel tiles
    int wt = bid % 10; bid /= 10;          // 10 width tiles
    int h  = bid % HH;
    int b  = bid / HH;
    int tx = threadIdx.x & 31, ty = threadIdx.x >> 5;   // 32 x 8
    int w0 = wt * 32, c0 = ct * 32;

    #pragma unroll
    for (int i = 0; i < 4; i++) {
        int c = c0 + ty + 8 * i;
        int w = w0 + tx;
        float v = 0.f;
        if (w < WW) v = img[((b * C2D + c) * HH + h) * WW + w];
        tile[ty + 8 * i][tx] = v;
    }
    __syncthreads();
    #pragma unroll
    for (int i = 0; i < 4; i++) {
        int w = w0 + ty + 8 * i;
        int c = c0 + tx;
        if (w < WW) img_bf[((b * HH + h) * WW + w) * C2D + c] = f2bf(tile[tx][ty + 8 * i]);
    }
}

// ---------------------------------------------------------------------------
// K2 (round-8): BN1 stats as h0 row-stats via MFMA. Replaces k_xtx.
// Identity: q[t]=w_t^T S w_t = sum_r h0[r][t]^2, wc[t]=sum_r h0[r][t] where
// h0 = X @ w1^T (b1 cancels out of v and sh). So BN1 stats are per-channel
// sum/ssq of GEMM1's output, computed with the SAME bf16 MFMA pipeline k_main
// uses (more self-consistent than f32 X^TX; bf16 effect on m,v ~1e-6 rel).
// k_xtx's scalar loop was latency-bound (~150us invariant to blocks/atomics/
// prefetch, VGPR 36, ~2 LDS reads in flight vs 120cy latency); this is a
// streaming GEMM: 51 MB HBM (~9us floor), 200K MFMAs, 160K slot atomics.
// Determinism: fixed-order in-lane, shfl, LDS cross-wave, u64 fixed-point.
// ---------------------------------------------------------------------------
#define H0_ROWS   320
#define H0_BLOCKS (NPTS / H0_ROWS)         // 625

__global__ __launch_bounds__(256) void k_h0stats(
        const float* __restrict__ x, const ushort* __restrict__ wb,
        unsigned long long* __restrict__ hs64,
        unsigned long long* __restrict__ hq64) {
    __shared__ float red[4][256];          // [wave][c + 128*stat]
    const ushort* w1b = wb + WB_W1;
    int t = threadIdx.x, lane = t & 63, wv = t >> 6;
    int l15 = lane & 15, lq = lane >> 4;
    float psum[8], pssq[8];
    #pragma unroll
    for (int nt = 0; nt < 8; nt++) { psum[nt] = 0.f; pssq[nt] = 0.f; }

    int r0 = blockIdx.x * H0_ROWS;
    #pragma unroll 1
    for (int ch = 0; ch < 5; ch++) {
        const float* xr = x + (long)(r0 + ch * 64 + wv * 16 + l15) * C3D;
        float4 xa0 = *(const float4*)(xr + lq * 8);
        float4 xa1 = *(const float4*)(xr + lq * 8 + 4);
        float4 xb0 = *(const float4*)(xr + 32 + lq * 8);
        float4 xb1 = *(const float4*)(xr + 32 + lq * 8 + 4);
        s16x8 af0 = pack_bf8(xa0, xa1);
        s16x8 af1 = pack_bf8(xb0, xb1);
        #pragma unroll
        for (int nt = 0; nt < 8; nt++) {
            f32x4 acc = {0.f, 0.f, 0.f, 0.f};
            s16x8 bf0 = *(const s16x8*)(w1b + (nt * 16 + l15) * 64 + lq * 8);
            s16x8 bf1 = *(const s16x8*)(w1b + (nt * 16 + l15) * 64 + 32 + lq * 8);
            acc = __builtin_amdgcn_mfma_f32_16x16x32_bf16(af0, bf0, acc, 0, 0, 0);
            acc = __builtin_amdgcn_mfma_f32_16x16x32_bf16(af1, bf1, acc, 0, 0, 0);
            psum[nt] += acc[0] + acc[1] + acc[2] + acc[3];
            pssq[nt] += acc[0]*acc[0] + acc[1]*acc[1] + acc[2]*acc[2] + acc[3]*acc[3];
        }
    }
    // reduce over lq (lanes sharing l15): channel totals for the wave's rows
    #pragma unroll
    for (int nt = 0; nt < 8; nt++) {
        psum[nt] += __shfl_xor(psum[nt], 16, 64);
        psum[nt] += __shfl_xor(psum[nt], 32, 64);
        pssq[nt] += __shfl_xor(pssq[nt], 16, 64);
        pssq[nt] += __shfl_xor(pssq[nt], 32, 64);
    }
    if (lane < 16) {
        #pragma unroll
        for (int nt = 0; nt < 8; nt++) {
            red[wv][nt * 16 + l15]       = psum[nt];
            red[wv][128 + nt * 16 + l15] = pssq[nt];
        }
    }
    __syncthreads();
    {
        float v = red[0][t] + red[1][t] + red[2][t] + red[3][t];  // fixed order
        int c = t & 127;
        int slot = blockIdx.x & 15;
        if (t < 128) atomic_fx(&hs64[c * 16 + slot], v);
        else         atomic_fx(&hq64[c * 16 + slot], v);
    }
}

// ---------------------------------------------------------------------------
// K3 (round-8): trivial BN1 finalize from h0 sum/ssq slots (b1 cancels).
// ---------------------------------------------------------------------------
__global__ void k_fin1(const unsigned long long* __restrict__ hs64,
                       const unsigned long long* __restrict__ hq64,
                       const float* __restrict__ g, const float* __restrict__ be,
                       float* __restrict__ s, float* __restrict__ sh) {
    int c = threadIdx.x;   // 128
    long long si = 0, qi = 0;
    #pragma unroll
    for (int i = 0; i < 16; i++) {
        si += (long long)hs64[c * 16 + i];
        qi += (long long)hq64[c * 16 + i];
    }
    float S = (float)((double)si * FXI);
    float Q = (float)((double)qi * FXI);
    const float invN = 1.f / (float)NPTS;
    float m = S * invN;
    float v = Q * invN - m * m;
    float sc = g[c] * rsqrtf(v + 1e-5f);
    s[c] = sc;
    sh[c] = be[c] - m * sc;
}

// ---------------------------------------------------------------------------
// K4: fused main kernel (round-6 structure, unchanged: all-N-split,
// reg-resident weight slices, 56 KB weights/wave, 7 barriers, 156 us).
// ---------------------------------------------------------------------------
__global__ __launch_bounds__(256, 3) void k_main(
    const float* __restrict__ x, const int* __restrict__ coords,
    const ushort* __restrict__ img_bf, const float* __restrict__ P2,
    const ushort* __restrict__ wb,
    const float* __restrict__ bn1s, const float* __restrict__ bn1sh,
    const float* __restrict__ b2, const float* __restrict__ ab1,
    const float* __restrict__ ab2, const float* __restrict__ fb,
    float* __restrict__ out,
    unsigned long long* __restrict__ sum64, unsigned long long* __restrict__ ssq64)
{
    __shared__ __align__(16) char smem[34816];
    ushort* combs  = (ushort*)smem;          // 64 x 264 bf16 (33792 B)
    float*  outs   = (float*)smem;           // 64 x 132 f32 (same footprint)
    float*  a_part = (float*)(smem + 33792); // 4 x 64 f32 (1024 B)

    const ushort* w1b  = wb + WB_W1;
    const ushort* w2b  = wb + WB_W2;
    const ushort* aw1b = wb + WB_AW1;
    const ushort* aw2b = wb + WB_AW2;
    const ushort* fwb  = wb + WB_FW;

    int t = threadIdx.x;
    int n0 = blockIdx.x * 64;
    int lane = t & 63, wv = t >> 6;
    int l15 = lane & 15, lq = lane >> 4;
    int m0 = wv * 16;
    int cb = wv * 32;                        // N-split column base

    // ---- P1a: projection, per-lane (row = m0 + (lane>>2), 4x redundant) ----
    int grow = m0 + (lane >> 2);
    int qc = lane & 3;
    int poff_[4]; float pwgt_[4];
    {
        int4 cd = *(const int4*)(coords + (long)(n0 + grow) * 4);
        int b = cd.x;
        float p0 = (float)cd.y * 0.05f;
        float p1 = (float)cd.z * 0.05f - 40.f;
        float p2 = (float)cd.w * 0.1f - 3.f;
        const float* P = P2 + b * 12;
        float cam0 = P[0] * p0 + P[1] * p1 + P[2]  * p2 + P[3];
        float cam1 = P[4] * p0 + P[5] * p1 + P[6]  * p2 + P[7];
        float cam2 = P[8] * p0 + P[9] * p1 + P[10] * p2 + P[11];
        float d = cam2 + 1e-8f;
        float px = cam0 / d, py = cam1 / d;
        float gx = fminf(fmaxf(px / (float)WW * 2.f - 1.f, -1.f), 1.f);
        float gy = fminf(fmaxf(py / (float)HH * 2.f - 1.f, -1.f), 1.f);
        float ix = ((gx + 1.f) * (float)WW - 1.f) * 0.5f;
        float iy = ((gy + 1.f) * (float)HH - 1.f) * 0.5f;
        float x0f = floorf(ix), y0f = floorf(iy);
        float wx = ix - x0f, wy = iy - y0f;
        int x0 = (int)x0f, y0 = (int)y0f;
        #pragma unroll
        for (int j = 0; j < 4; j++) {
            int xc = x0 + (j & 1), yc = y0 + (j >> 1);
            float wgt = ((j & 1) ? wx : 1.f - wx) * ((j >> 1) ? wy : 1.f - wy);
            bool valid = (xc >= 0) && (xc < WW) && (yc >= 0) && (yc < HH);
            int xcc = min(max(xc, 0), WW - 1), ycc = min(max(yc, 0), HH - 1);
            poff_[j] = ((b * HH + ycc) * WW + xcc) * C2D;
            pwgt_[j] = valid ? wgt : 0.f;
        }
    }

    // ---- P1b: bilinear gather, ONE 8-channel group at a time (8 accs) ----
    #pragma unroll
    for (int g = 0; g < 4; g++) {
        float a8[8];
        #pragma unroll
        for (int e = 0; e < 8; e++) a8[e] = 0.f;
        #pragma unroll
        for (int j = 0; j < 4; j++) {
            s16x8 v = *(const s16x8*)(img_bf + poff_[j] + qc * 32 + g * 8);
            float wgt = pwgt_[j];
            #pragma unroll
            for (int e = 0; e < 8; e++)
                a8[e] += wgt * bf2f((ushort)v[e]);
        }
        s16x8 o;
        #pragma unroll
        for (int e = 0; e < 8; e++) o[e] = (short)f2bf(a8[e]);
        *(s16x8*)(combs + grow * 264 + 128 + qc * 32 + g * 8) = o;
    }

    // ---- P1c: GEMM1 A-operand: load from global, pack to bf16 ----
    s16x8 af0, af1;
    {
        const float* xr = x + (long)(n0 + m0 + l15) * C3D;
        float4 xa0 = *(const float4*)(xr + lq * 8);
        float4 xa1 = *(const float4*)(xr + lq * 8 + 4);
        float4 xb0 = *(const float4*)(xr + 32 + lq * 8);
        float4 xb1 = *(const float4*)(xr + 32 + lq * 8 + 4);
        af0 = pack_bf8(xa0, xa1);
        af1 = pack_bf8(xb0, xb1);
    }

    // ---- P1d: GEMM1 (K=64, M-split) + BN1 + relu -> combs[:, 0:128) ----
    #pragma unroll
    for (int nt = 0; nt < 8; nt++) {
        f32x4 acc = {0.f, 0.f, 0.f, 0.f};
        s16x8 bf0 = *(const s16x8*)(w1b + (nt * 16 + l15) * 64 + lq * 8);
        s16x8 bf1 = *(const s16x8*)(w1b + (nt * 16 + l15) * 64 + 32 + lq * 8);
        acc = __builtin_amdgcn_mfma_f32_16x16x32_bf16(af0, bf0, acc, 0, 0, 0);
        acc = __builtin_amdgcn_mfma_f32_16x16x32_bf16(af1, bf1, acc, 0, 0, 0);
        int c = nt * 16 + l15;
        float sc = bn1s[c], shf = bn1sh[c];
        #pragma unroll
        for (int r = 0; r < 4; r++)
            combs[(m0 + lq * 4 + r) * 264 + c] = f2bf(fmaxf(acc[r] * sc + shf, 0.f));
    }
    __syncthreads();   // B1: h + ifeat complete for ALL rows

    // ---- P2: GEMM2 N-split (wave's 32 cols x all 64 rows), w2 slice 8 KB ----
    f32x4 vacc[4][2];
    #pragma unroll
    for (int nt2 = 0; nt2 < 2; nt2++) {
        int c = cb + nt2 * 16 + l15;
        s16x8 wf[4];
        #pragma unroll
        for (int s = 0; s < 4; s++)
            wf[s] = *(const s16x8*)(w2b + c * 128 + s * 32 + lq * 8);
        #pragma unroll
        for (int mt = 0; mt < 4; mt++) {
            s16x8 ah[4];
            #pragma unroll
            for (int s = 0; s < 4; s++)
                ah[s] = *(const s16x8*)(combs + (mt * 16 + l15) * 264 + s * 32 + lq * 8);
            f32x4 acc = {0.f, 0.f, 0.f, 0.f};
            #pragma unroll
            for (int s = 0; s < 4; s++)
                acc = __builtin_amdgcn_mfma_f32_16x16x32_bf16(ah[s], wf[s], acc, 0, 0, 0);
            vacc[mt][nt2] = acc;
        }
    }
    __syncthreads();   // B2: all h reads done -> vfeat may overwrite h

    #pragma unroll
    for (int nt2 = 0; nt2 < 2; nt2++) {
        int c = cb + nt2 * 16 + l15;
        float bb = b2[c];
        #pragma unroll
        for (int mt = 0; mt < 4; mt++)
            #pragma unroll
            for (int r = 0; r < 4; r++)
                combs[(mt * 16 + lq * 4 + r) * 264 + c] = f2bf(vacc[mt][nt2][r] + bb);
    }
    __syncthreads();   // B3: vfeat complete; combs = [vfeat | ifeat]

    // ---- P3: att1 N-split, aw1 slice hoisted (16 KB once per wave) ----
    float sp[4][4];
    #pragma unroll
    for (int mt = 0; mt < 4; mt++)
        #pragma unroll
        for (int r = 0; r < 4; r++) sp[mt][r] = 0.f;
    #pragma unroll
    for (int nt2 = 0; nt2 < 2; nt2++) {
        int c = cb + nt2 * 16 + l15;
        s16x8 wf[8];
        #pragma unroll
        for (int s = 0; s < 8; s++)
            wf[s] = *(const s16x8*)(aw1b + c * 256 + s * 32 + lq * 8);
        float bb = ab1[c];
        float w2c = bf2f(aw2b[c]);
        #pragma unroll
        for (int mt = 0; mt < 4; mt++) {
            s16x8 afm[8];
            #pragma unroll
            for (int s = 0; s < 8; s++)
                afm[s] = *(const s16x8*)(combs + (mt * 16 + l15) * 264 + s * 32 + lq * 8);
            f32x4 acc = {0.f, 0.f, 0.f, 0.f};
            #pragma unroll
            for (int s = 0; s < 8; s++)
                acc = __builtin_amdgcn_mfma_f32_16x16x32_bf16(afm[s], wf[s], acc, 0, 0, 0);
            #pragma unroll
            for (int r = 0; r < 4; r++)
                sp[mt][r] += fmaxf(acc[r] + bb, 0.f) * w2c;
        }
    }
    #pragma unroll
    for (int d = 1; d < 16; d <<= 1) {
        #pragma unroll
        for (int mt = 0; mt < 4; mt++)
            #pragma unroll
            for (int r = 0; r < 4; r++)
                sp[mt][r] += __shfl_xor(sp[mt][r], d, 64);
    }
    if (l15 == 0) {
        #pragma unroll
        for (int mt = 0; mt < 4; mt++) {
            f32x4 v = {sp[mt][0], sp[mt][1], sp[mt][2], sp[mt][3]};
            *(f32x4*)(a_part + wv * 64 + mt * 16 + lq * 4) = v;
        }
    }
    __syncthreads();   // B4: a_part complete AND all att combs reads done

    // ---- P4: gate combs in place (wave-private rows), a computed per-lane ----
    {
        int row = m0 + l15;                // wave wv gates its own 16 rows
        float s0 = ab2[0] + a_part[row] + a_part[64 + row] + a_part[128 + row]
                 + a_part[192 + row];
        float a = 1.f / (1.f + expf(-s0));
        #pragma unroll
        for (int j = 0; j < 8; j++) {
            int ch = lq * 8 + j;           // 32 chunks of 8 cols per row
            float f = (ch < 16) ? a : 1.f - a;
            ushort* p = combs + row * 264 + ch * 8;
            s16x8 v = *(s16x8*)p;
            s16x8 o;
            #pragma unroll
            for (int e = 0; e < 8; e++) o[e] = (short)f2bf(bf2f((ushort)v[e]) * f);
            *(s16x8*)p = o;
        }
    }
    __syncthreads();   // B5: gated combs complete

    // ---- P5: fusion N-split (K=256), fw slice hoisted, ONE acc set ----
    f32x4 facc[4][2];
    #pragma unroll
    for (int nt2 = 0; nt2 < 2; nt2++) {
        int c = cb + nt2 * 16 + l15;
        s16x8 wf[8];
        #pragma unroll
        for (int s = 0; s < 8; s++)
            wf[s] = *(const s16x8*)(fwb + c * 256 + s * 32 + lq * 8);
        #pragma unroll
        for (int mt = 0; mt < 4; mt++) {
            s16x8 afm[8];
            #pragma unroll
            for (int s = 0; s < 8; s++)
                afm[s] = *(const s16x8*)(combs + (mt * 16 + l15) * 264 + s * 32 + lq * 8);
            f32x4 acc = {0.f, 0.f, 0.f, 0.f};
            #pragma unroll
            for (int s = 0; s < 8; s++)
                acc = __builtin_amdgcn_mfma_f32_16x16x32_bf16(afm[s], wf[s], acc, 0, 0, 0);
            facc[mt][nt2] = acc;
        }
    }
    __syncthreads();   // B6: all fusion reads done -> outs may alias combs

    #pragma unroll
    for (int nt2 = 0; nt2 < 2; nt2++) {
        int c = cb + nt2 * 16 + l15;
        float bb = fb[c];
        #pragma unroll
        for (int mt = 0; mt < 4; mt++)
            #pragma unroll
            for (int r = 0; r < 4; r++)
                outs[(mt * 16 + lq * 4 + r) * 132 + c] = facc[mt][nt2][r] + bb;
    }
    __syncthreads();   // B7: outs complete

    // ---- P6: coalesced global store + BN2 stats (fixed-point u64) ----
    {
        float4* og = (float4*)(out + (long)n0 * OUTC);
        #pragma unroll
        for (int i = 0; i < 8; i++) {
            int f4 = t + 256 * i;              // 2048 float4 = 64 rows x 32
            int row = f4 >> 5, c4 = f4 & 31;
            float4 v = *(const float4*)(outs + row * 132 + c4 * 4);
            og[row * 32 + c4] = v;
        }
        int slot = blockIdx.x & 15;
        if (t < 128) {
            float S = 0.f;
            #pragma unroll 8
            for (int row = 0; row < 64; row++) S += outs[row * 132 + t];
            atomic_fx(&sum64[t * 16 + slot], S);
        } else {
            int c = t - 128;
            float Q = 0.f;
            #pragma unroll 8
            for (int row = 0; row < 64; row++) { float v = outs[row * 132 + c]; Q += v * v; }
            atomic_fx(&ssq64[c * 16 + slot], Q);
        }
    }
}

// ---------------------------------------------------------------------------
// K6: BN2 finalize (per-block from 16-slot u64 sums, fixed order) + relu.
// ---------------------------------------------------------------------------
__global__ __launch_bounds__(256) void k_bnf(float* __restrict__ out,
                                             const unsigned long long* __restrict__ sum64,
                                             const unsigned long long* __restrict__ ssq64,
                                             const float* __restrict__ g,
                                             const float* __restrict__ b) {
    __shared__ float s_s[128], s_sh[128];
    int t = threadIdx.x;
    if (t < 128) {
        long long si = 0, qi = 0;
        #pragma unroll
        for (int i = 0; i < 16; i++) {
            si += (long long)sum64[t * 16 + i];
            qi += (long long)ssq64[t * 16 + i];
        }
        float S = (float)((double)si * FXI);
        float Q = (float)((double)qi * FXI);
        const float invN = 1.f / (float)NPTS;
        float m = S * invN;
        float v = Q * invN - m * m;
        float sc = g[t] * rsqrtf(v + 1e-5f);
        s_s[t] = sc;
        s_sh[t] = b[t] - m * sc;
    }
    __syncthreads();

    long i = (long)blockIdx.x * 256 + t;   // over 6.4M float4
    float4* p = (float4*)out;
    float4 v = p[i];
    int c4 = (int)(i & 31);
    float4 sv  = *(const float4*)(s_s + c4 * 4);
    float4 shv = *(const float4*)(s_sh + c4 * 4);
    v.x = fmaxf(v.x * sv.x + shv.x, 0.f);
    v.y = fmaxf(v.y * sv.y + shv.y, 0.f);
    v.z = fmaxf(v.z * sv.z + shv.z, 0.f);
    v.w = fmaxf(v.w * sv.w + shv.w, 0.f);
    p[i] = v;
}

// ---------------------------------------------------------------------------
extern "C" void kernel_launch(void* const* d_in, const int* in_sizes, int n_in,
                              void* d_out, int out_size, void* d_ws, size_t ws_size,
                              hipStream_t stream) {
    const float* x      = (const float*)d_in[0];
    const int*   coords = (const int*)d_in[1];
    const float* img    = (const float*)d_in[2];
    const float* P2     = (const float*)d_in[3];
    const float* w1     = (const float*)d_in[4];
    const float* b1     = (const float*)d_in[5];
    const float* g1     = (const float*)d_in[6];
    const float* be1    = (const float*)d_in[7];
    const float* w2     = (const float*)d_in[8];
    const float* b2     = (const float*)d_in[9];
    const float* aw1    = (const float*)d_in[10];
    const float* ab1    = (const float*)d_in[11];
    const float* aw2    = (const float*)d_in[12];
    const float* ab2    = (const float*)d_in[13];
    const float* fw     = (const float*)d_in[14];
    const float* fb     = (const float*)d_in[15];
    const float* gf     = (const float*)d_in[16];
    const float* bef    = (const float*)d_in[17];
    float* out = (float*)d_out;
    (void)b1;   // cancels out of BN1 algebra (mean-shift only)

    float* wsf = (float*)d_ws;
    ushort* wb = (ushort*)wsf;                                   // 90240 ushorts
    unsigned long long* hs64  = (unsigned long long*)(wsf + WS_H0S);
    unsigned long long* hq64  = (unsigned long long*)(wsf + WS_H0Q);
    unsigned long long* sum64 = (unsigned long long*)(wsf + WS_SUM64);
    unsigned long long* ssq64 = (unsigned long long*)(wsf + WS_SSQ64);
    float* zero_base = wsf + WS_H0S;
    float* s1  = wsf + WS_DERIV;
    float* sh1 = s1 + 128;
    ushort* img_bf = (ushort*)(wsf + WS_IMG);                    // 15,335,424 ushorts

    // K1: transpose image (bf16) + zero stats + bf16 weights
    k_transpose<<<BB * HH * 10 * 4, 256, 0, stream>>>(img, img_bf, zero_base,
                                                      w1, w2, aw1, aw2, fw, wb);
    // K2: BN1 stats = per-channel sum/ssq of h0 = X@w1^T (MFMA streaming)
    k_h0stats<<<H0_BLOCKS, 256, 0, stream>>>(x, wb, hs64, hq64);
    // K3: trivial BN1 finalize
    k_fin1<<<1, 128, 0, stream>>>(hs64, hq64, g1, be1, s1, sh1);
    // K4: fused main (MFMA), 3125 blocks, all-N-split + reg-resident weights
    k_main<<<NPTS / 64, 256, 0, stream>>>(x, coords, img_bf, P2, wb, s1, sh1,
                                          b2, ab1, ab2, fb, out, sum64, ssq64);
    // K6: BN2 finalize (per-block, deterministic) + relu
    k_bnf<<<NPTS * OUTC / 4 / 256, 256, 0, stream>>>(out, sum64, ssq64, gf, bef);
}